// Round 1
// baseline (413.090 us; speedup 1.0000x reference)
//
#include <hip/hip_runtime.h>
#include <hip/hip_fp16.h>

#define D_MODEL 512
#define D_FF    2048
#define NEXP    8
#define NTOK    4096
#define NPAIR   8192
#define DUMMY   NPAIR
#define LSTRIDE 4224   // 4096 + 128 pad

typedef _Float16 half8  __attribute__((ext_vector_type(8)));
typedef _Float16 half2v __attribute__((ext_vector_type(2)));
typedef float    f32x4  __attribute__((ext_vector_type(4)));

__device__ __forceinline__ void gload16(const void* g, void* l) {
  __builtin_amdgcn_global_load_lds(
      (const __attribute__((address_space(1))) unsigned*)g,
      (__attribute__((address_space(3))) unsigned*)l, 16, 0, 0);
}

// ---------------- init: zero out + meta, fill lists with DUMMY ----------------
__global__ void k_init(float* __restrict__ out, int* __restrict__ lists,
                       int* __restrict__ meta_i) {
  int idx = blockIdx.x * blockDim.x + threadIdx.x;
  int stride = gridDim.x * blockDim.x;
  float4* o4 = (float4*)out;
  for (int i = idx; i < (NTOK * D_MODEL / 4); i += stride)
    o4[i] = float4{0.f, 0.f, 0.f, 0.f};
  if (idx < 2) out[NTOK * D_MODEL + idx] = 0.f;
  for (int i = idx; i < NEXP * LSTRIDE; i += stride) lists[i] = DUMMY;
  if (idx < 32) meta_i[idx] = 0;
}

// ---------------- x fp32 -> f16 ----------------
__global__ void k_cvtx(const float* __restrict__ x, _Float16* __restrict__ xb) {
  int idx = blockIdx.x * blockDim.x + threadIdx.x;
  int base = idx * 8;
  if (base >= NTOK * D_MODEL) return;
  float4 a = *(const float4*)(x + base);
  float4 b = *(const float4*)(x + base + 4);
  half8 h = {(_Float16)a.x, (_Float16)a.y, (_Float16)a.z, (_Float16)a.w,
             (_Float16)b.x, (_Float16)b.y, (_Float16)b.z, (_Float16)b.w};
  *(half8*)(xb + base) = h;
}

// ---------------- transpose + convert: src [R][C] f32 -> dst [C][R] f16 ------
__global__ void k_transcvt(const float* __restrict__ src, _Float16* __restrict__ dst,
                           int R, int C) {
  __shared__ float t[64][65];
  size_t mat = (size_t)R * C;
  src += (size_t)blockIdx.z * mat;
  dst += (size_t)blockIdx.z * mat;
  int rb = blockIdx.y * 64, cb = blockIdx.x * 64;
  int tid = threadIdx.x;
  int tx = tid & 15, ty = tid >> 4;
#pragma unroll
  for (int i = 0; i < 4; i++) {
    float4 v = *(const float4*)(src + (size_t)(rb + ty + i * 16) * C + cb + tx * 4);
    t[ty + i * 16][tx * 4 + 0] = v.x;
    t[ty + i * 16][tx * 4 + 1] = v.y;
    t[ty + i * 16][tx * 4 + 2] = v.z;
    t[ty + i * 16][tx * 4 + 3] = v.w;
  }
  __syncthreads();
  int tx2 = tid & 31, ty2 = tid >> 5;
#pragma unroll
  for (int i = 0; i < 8; i++) {
    int c = ty2 + i * 8;
    int r = tx2 * 2;
    half2v p = {(_Float16)t[r][c], (_Float16)t[r + 1][c]};
    *(half2v*)(dst + (size_t)(cb + c) * R + rb + r) = p;
  }
}

// ---------------- router: logits, softmax, top2, lists, loss partials --------
__global__ __launch_bounds__(256) void k_router(
    const float* __restrict__ x, const float* __restrict__ rw,
    int* __restrict__ lists, int* __restrict__ cnt, float* __restrict__ wcomb,
    float* __restrict__ imp_sum, float* __restrict__ load_sum,
    float* __restrict__ z_sum) {
  __shared__ float s_imp[NEXP];
  __shared__ float s_load[NEXP];
  __shared__ float s_z;
  int tid = threadIdx.x;
  if (tid < NEXP) { s_imp[tid] = 0.f; s_load[tid] = 0.f; }
  if (tid == 0) s_z = 0.f;
  __syncthreads();
  int wave = tid >> 6, lane = tid & 63;
  int n = blockIdx.x * 4 + wave;
  const float* xr = x + (size_t)n * D_MODEL;
  float acc[8] = {0, 0, 0, 0, 0, 0, 0, 0};
  float4 v0 = *(const float4*)(xr + lane * 8);
  float4 v1 = *(const float4*)(xr + lane * 8 + 4);
  float xs[8] = {v0.x, v0.y, v0.z, v0.w, v1.x, v1.y, v1.z, v1.w};
#pragma unroll
  for (int j = 0; j < 8; j++) {
    const float4* w4 = (const float4*)(rw + (size_t)(lane * 8 + j) * NEXP);
    float4 wa = w4[0], wb = w4[1];
    acc[0] += xs[j] * wa.x; acc[1] += xs[j] * wa.y;
    acc[2] += xs[j] * wa.z; acc[3] += xs[j] * wa.w;
    acc[4] += xs[j] * wb.x; acc[5] += xs[j] * wb.y;
    acc[6] += xs[j] * wb.z; acc[7] += xs[j] * wb.w;
  }
#pragma unroll
  for (int off = 32; off >= 1; off >>= 1) {
#pragma unroll
    for (int e = 0; e < 8; e++) acc[e] += __shfl_xor(acc[e], off);
  }
  if (lane == 0) {
    float z = 0.f;
#pragma unroll
    for (int e = 0; e < 8; e++) z += acc[e] * acc[e];
    float m = acc[0];
#pragma unroll
    for (int e = 1; e < 8; e++) m = fmaxf(m, acc[e]);
    float p[8], s = 0.f;
#pragma unroll
    for (int e = 0; e < 8; e++) { p[e] = expf(acc[e] - m); s += p[e]; }
    float inv = 1.f / s;
#pragma unroll
    for (int e = 0; e < 8; e++) p[e] *= inv;
    int e0 = 0; float p0 = p[0];
#pragma unroll
    for (int e = 1; e < 8; e++) if (p[e] > p0) { p0 = p[e]; e0 = e; }
    int e1 = -1; float p1 = -1.f;
#pragma unroll
    for (int e = 0; e < 8; e++) if (e != e0 && p[e] > p1) { p1 = p[e]; e1 = e; }
    float wsum = p0 + p1;
    int pos0 = atomicAdd(&cnt[e0], 1);
    lists[e0 * LSTRIDE + pos0] = 2 * n;
    wcomb[2 * n] = p0 / wsum;
    int pos1 = atomicAdd(&cnt[e1], 1);
    lists[e1 * LSTRIDE + pos1] = 2 * n + 1;
    wcomb[2 * n + 1] = p1 / wsum;
#pragma unroll
    for (int e = 0; e < 8; e++) atomicAdd(&s_imp[e], p[e]);
    atomicAdd(&s_load[e0], 1.f);
    atomicAdd(&s_z, z);
  }
  __syncthreads();
  if (tid < NEXP) {
    atomicAdd(&imp_sum[tid], s_imp[tid]);
    atomicAdd(&load_sum[tid], s_load[tid]);
  }
  if (tid == 0) atomicAdd(z_sum, s_z);
}

// ---------------- losses ----------------
__global__ void k_finalize(const float* __restrict__ imp, const float* __restrict__ loadS,
                           const float* __restrict__ zS, float* __restrict__ out) {
  if (threadIdx.x == 0 && blockIdx.x == 0) {
    float s = 0.f;
    for (int e = 0; e < 8; e++)
      s += (imp[e] * (1.f / 4096.f)) * (loadS[e] * (1.f / 4096.f));
    out[NTOK * D_MODEL] = 8.f * s * 0.01f;
    out[NTOK * D_MODEL + 1] = (zS[0] * (1.f / (4096.f * 8.f))) * 1e-4f;
  }
}

// ---------------- gemm1: h[pair] = silu(x@w1) * (x@w3), f16 out --------------
__global__ __launch_bounds__(256) void k_gemm1(
    const _Float16* __restrict__ xb, const _Float16* __restrict__ w1t,
    const _Float16* __restrict__ w3t, _Float16* __restrict__ h,
    const int* __restrict__ lists, const int* __restrict__ cnt) {
  int e = blockIdx.z, mt = blockIdx.y, nt = blockIdx.x;
  if (mt * 128 >= cnt[e]) return;
  __shared__ __align__(16) _Float16 As[128 * 64];
  __shared__ __align__(16) _Float16 B1s[128 * 64];
  __shared__ __align__(16) _Float16 B3s[128 * 64];
  __shared__ int toks[128];
  int tid = threadIdx.x, lane = tid & 63, w = tid >> 6;
  if (tid < 128) toks[tid] = lists[e * LSTRIDE + mt * 128 + tid];
  __syncthreads();
  const _Float16* w1e = w1t + (size_t)e * D_FF * D_MODEL;
  const _Float16* w3e = w3t + (size_t)e * D_FF * D_MODEL;
  int n0 = nt * 128;
  const _Float16 *aS[4], *b1S[4], *b3S[4];
#pragma unroll
  for (int c = 0; c < 4; c++) {
    int rt = w * 32 + c * 8 + (lane >> 3);
    int ch = (lane & 7) ^ (rt & 7);
    aS[c] = xb + (size_t)(toks[rt] >> 1) * D_MODEL + ch * 8;
    b1S[c] = w1e + (size_t)(n0 + rt) * D_MODEL + ch * 8;
    b3S[c] = w3e + (size_t)(n0 + rt) * D_MODEL + ch * 8;
  }
  f32x4 acc1[4][4] = {};
  f32x4 acc3[4][4] = {};
  int wr = (w >> 1) * 64, wc = (w & 1) * 64;
  for (int k0 = 0; k0 < D_MODEL; k0 += 64) {
#pragma unroll
    for (int c = 0; c < 4; c++) {
      int rb = (w * 32 + c * 8) * 64;
      gload16(aS[c] + k0, As + rb);
      gload16(b1S[c] + k0, B1s + rb);
      gload16(b3S[c] + k0, B3s + rb);
    }
    __syncthreads();
#pragma unroll
    for (int s = 0; s < 2; s++) {
      int cidx = s * 4 + (lane >> 4);
      half8 af[4], b1f[4], b3f[4];
#pragma unroll
      for (int i = 0; i < 4; i++) {
        int r = wr + i * 16 + (lane & 15);
        af[i] = *(const half8*)(As + r * 64 + ((cidx ^ (r & 7)) << 3));
      }
#pragma unroll
      for (int j = 0; j < 4; j++) {
        int r = wc + j * 16 + (lane & 15);
        int off = r * 64 + ((cidx ^ (r & 7)) << 3);
        b1f[j] = *(const half8*)(B1s + off);
        b3f[j] = *(const half8*)(B3s + off);
      }
#pragma unroll
      for (int i = 0; i < 4; i++) {
#pragma unroll
        for (int j = 0; j < 4; j++) {
          acc1[i][j] = __builtin_amdgcn_mfma_f32_16x16x32_f16(af[i], b1f[j], acc1[i][j], 0, 0, 0);
          acc3[i][j] = __builtin_amdgcn_mfma_f32_16x16x32_f16(af[i], b3f[j], acc3[i][j], 0, 0, 0);
        }
      }
    }
    __syncthreads();
  }
#pragma unroll
  for (int i = 0; i < 4; i++) {
    int rbase = wr + i * 16 + ((lane >> 4) << 2);
#pragma unroll
    for (int r = 0; r < 4; r++) {
      int m = rbase + r;
      int pair = toks[m];
      _Float16* hrow = h + (size_t)pair * D_FF + n0 + wc;
#pragma unroll
      for (int j = 0; j < 4; j++) {
        float g = acc1[i][j][r], u = acc3[i][j][r];
        float val = (g / (1.f + __expf(-g))) * u;
        hrow[j * 16 + (lane & 15)] = (_Float16)val;
      }
    }
  }
}

// ---------------- gemm2: out[token] += wcomb * (h[pair] @ w2) ----------------
__global__ __launch_bounds__(256) void k_gemm2(
    const _Float16* __restrict__ h, const _Float16* __restrict__ w2t,
    float* __restrict__ out, const int* __restrict__ lists,
    const int* __restrict__ cnt, const float* __restrict__ wcomb) {
  int e = blockIdx.z, mt = blockIdx.y, nt = blockIdx.x;
  if (mt * 128 >= cnt[e]) return;
  __shared__ __align__(16) _Float16 As[128 * 64];
  __shared__ __align__(16) _Float16 Bs[64 * 64];
  __shared__ int toks[128];
  __shared__ float wcs[128];
  int tid = threadIdx.x, lane = tid & 63, w = tid >> 6;
  if (tid < 128) {
    int p = lists[e * LSTRIDE + mt * 128 + tid];
    toks[tid] = p;
    wcs[tid] = (p < NPAIR) ? wcomb[p] : 0.f;
  }
  __syncthreads();
  const _Float16* w2e = w2t + (size_t)e * D_MODEL * D_FF;
  int n0 = nt * 64;
  const _Float16 *aS[4], *bS[2];
#pragma unroll
  for (int c = 0; c < 4; c++) {
    int rt = w * 32 + c * 8 + (lane >> 3);
    int ch = (lane & 7) ^ (rt & 7);
    aS[c] = h + (size_t)toks[rt] * D_FF + ch * 8;
  }
#pragma unroll
  for (int c = 0; c < 2; c++) {
    int rt = w * 16 + c * 8 + (lane >> 3);
    int ch = (lane & 7) ^ (rt & 7);
    bS[c] = w2e + (size_t)(n0 + rt) * D_FF + ch * 8;
  }
  f32x4 acc[4][2] = {};
  int wr = (w >> 1) * 64, wc = (w & 1) * 32;
  for (int k0 = 0; k0 < D_FF; k0 += 64) {
#pragma unroll
    for (int c = 0; c < 4; c++) gload16(aS[c] + k0, As + (w * 32 + c * 8) * 64);
#pragma unroll
    for (int c = 0; c < 2; c++) gload16(bS[c] + k0, Bs + (w * 16 + c * 8) * 64);
    __syncthreads();
#pragma unroll
    for (int s = 0; s < 2; s++) {
      int cidx = s * 4 + (lane >> 4);
      half8 af[4], bf[2];
#pragma unroll
      for (int i = 0; i < 4; i++) {
        int r = wr + i * 16 + (lane & 15);
        af[i] = *(const half8*)(As + r * 64 + ((cidx ^ (r & 7)) << 3));
      }
#pragma unroll
      for (int j = 0; j < 2; j++) {
        int r = wc + j * 16 + (lane & 15);
        bf[j] = *(const half8*)(Bs + r * 64 + ((cidx ^ (r & 7)) << 3));
      }
#pragma unroll
      for (int i = 0; i < 4; i++) {
#pragma unroll
        for (int j = 0; j < 2; j++)
          acc[i][j] = __builtin_amdgcn_mfma_f32_16x16x32_f16(af[i], bf[j], acc[i][j], 0, 0, 0);
      }
    }
    __syncthreads();
  }
#pragma unroll
  for (int i = 0; i < 4; i++) {
    int rbase = wr + i * 16 + ((lane >> 4) << 2);
#pragma unroll
    for (int r = 0; r < 4; r++) {
      int m = rbase + r;
      int pair = toks[m];
      if (pair < NPAIR) {
        float wv = wcs[m];
        float* orow = out + (size_t)(pair >> 1) * D_MODEL + n0 + wc;
#pragma unroll
        for (int j = 0; j < 2; j++)
          atomicAdd(&orow[j * 16 + (lane & 15)], acc[i][j][r] * wv);
      }
    }
  }
}

extern "C" void kernel_launch(void* const* d_in, const int* in_sizes, int n_in,
                              void* d_out, int out_size, void* d_ws, size_t ws_size,
                              hipStream_t stream) {
  const float* x = (const float*)d_in[0];
  const float* rw = (const float*)d_in[1];
  const float* w1 = (const float*)d_in[2];
  const float* w2 = (const float*)d_in[3];
  const float* w3 = (const float*)d_in[4];
  float* out = (float*)d_out;

  char* ws = (char*)d_ws;
  size_t o = 0;
  _Float16* w1t = (_Float16*)(ws + o); o += (size_t)NEXP * D_FF * D_MODEL * 2;
  _Float16* w3t = (_Float16*)(ws + o); o += (size_t)NEXP * D_FF * D_MODEL * 2;
  _Float16* w2t = (_Float16*)(ws + o); o += (size_t)NEXP * D_MODEL * D_FF * 2;
  _Float16* xb = (_Float16*)(ws + o); o += (size_t)(NTOK + 1) * D_MODEL * 2;
  _Float16* hbuf = (_Float16*)(ws + o); o += (size_t)(NPAIR + 1) * D_FF * 2;
  int* lists = (int*)(ws + o); o += (size_t)NEXP * LSTRIDE * 4;
  float* wcomb = (float*)(ws + o); o += (size_t)NPAIR * 4;
  int* meta = (int*)(ws + o);
  int* cnt = meta;
  float* imp = (float*)(ws + o + 32);
  float* loadS = (float*)(ws + o + 64);
  float* zS = (float*)(ws + o + 96);
  o += 128;
  if (ws_size < o) return;  // workspace too small — refuse to corrupt

  k_init<<<2048, 256, 0, stream>>>(out, lists, meta);
  k_cvtx<<<(NTOK * D_MODEL / 8 + 255) / 256, 256, 0, stream>>>(x, xb);
  k_transcvt<<<dim3(D_FF / 64, D_MODEL / 64, NEXP), 256, 0, stream>>>(w1, w1t, D_MODEL, D_FF);
  k_transcvt<<<dim3(D_FF / 64, D_MODEL / 64, NEXP), 256, 0, stream>>>(w3, w3t, D_MODEL, D_FF);
  k_transcvt<<<dim3(D_MODEL / 64, D_FF / 64, NEXP), 256, 0, stream>>>(w2, w2t, D_FF, D_MODEL);
  k_router<<<NTOK / 4, 256, 0, stream>>>(x, rw, lists, cnt, wcomb, imp, loadS, zS);
  k_finalize<<<1, 64, 0, stream>>>(imp, loadS, zS, out);
  k_gemm1<<<dim3(D_FF / 128, 32, NEXP), 256, 0, stream>>>(xb, w1t, w3t, hbuf, lists, cnt);
  k_gemm2<<<dim3(D_MODEL / 64, 32, NEXP), 256, 0, stream>>>(hbuf, w2t, out, lists, cnt, wcomb);
}

// Round 2
// 317.689 us; speedup vs baseline: 1.3003x; 1.3003x over previous
//
#include <hip/hip_runtime.h>
#include <hip/hip_fp16.h>

#define D_MODEL 512
#define D_FF    2048
#define NEXP    8
#define NTOK    4096
#define NPAIR   8192
#define DUMMY   NPAIR
#define LSTRIDE 4224   // 4096 + 128 pad

typedef _Float16 half8  __attribute__((ext_vector_type(8)));
typedef _Float16 half2v __attribute__((ext_vector_type(2)));
typedef float    f32x4  __attribute__((ext_vector_type(4)));

__device__ __forceinline__ void gload16(const void* g, void* l) {
  __builtin_amdgcn_global_load_lds(
      (const __attribute__((address_space(1))) unsigned*)g,
      (__attribute__((address_space(3))) unsigned*)l, 16, 0, 0);
}

// ---------------- x fp32 -> f16 ----------------
__global__ void k_cvtx(const float* __restrict__ x, _Float16* __restrict__ xb) {
  int idx = blockIdx.x * blockDim.x + threadIdx.x;
  int base = idx * 8;
  if (base >= NTOK * D_MODEL) return;
  float4 a = *(const float4*)(x + base);
  float4 b = *(const float4*)(x + base + 4);
  half8 h = {(_Float16)a.x, (_Float16)a.y, (_Float16)a.z, (_Float16)a.w,
             (_Float16)b.x, (_Float16)b.y, (_Float16)b.z, (_Float16)b.w};
  *(half8*)(xb + base) = h;
}

// ------------- merged transpose+convert for w1,w3,w2: [R][C]f32 -> [C][R]f16 -
__global__ void k_trans3(const float* __restrict__ w1, const float* __restrict__ w3,
                         const float* __restrict__ w2, _Float16* __restrict__ w1t,
                         _Float16* __restrict__ w3t, _Float16* __restrict__ w2t) {
  __shared__ float t[64][65];
  int bt = blockIdx.x;
  const float* src; _Float16* dst; int R, C, rb, cb;
  if (bt < 4096) {
    src = (bt < 2048) ? w1 : w3; dst = (bt < 2048) ? w1t : w3t;
    int tt = bt & 2047; int e = tt >> 8; int rem = tt & 255;
    R = D_MODEL; C = D_FF; rb = (rem >> 5) * 64; cb = (rem & 31) * 64;
    src += (size_t)e * R * C; dst += (size_t)e * R * C;
  } else {
    int tt = bt - 4096; int e = tt >> 8; int rem = tt & 255;
    src = w2; dst = w2t;
    R = D_FF; C = D_MODEL; rb = (rem >> 3) * 64; cb = (rem & 7) * 64;
    src += (size_t)e * R * C; dst += (size_t)e * R * C;
  }
  int tid = threadIdx.x;
  int tx = tid & 15, ty = tid >> 4;
#pragma unroll
  for (int i = 0; i < 4; i++) {
    float4 v = *(const float4*)(src + (size_t)(rb + ty + i * 16) * C + cb + tx * 4);
    t[ty + i * 16][tx * 4 + 0] = v.x;
    t[ty + i * 16][tx * 4 + 1] = v.y;
    t[ty + i * 16][tx * 4 + 2] = v.z;
    t[ty + i * 16][tx * 4 + 3] = v.w;
  }
  __syncthreads();
  int tx2 = tid & 31, ty2 = tid >> 5;
#pragma unroll
  for (int i = 0; i < 8; i++) {
    int c = ty2 + i * 8;
    int r = tx2 * 2;
    half2v p = {(_Float16)t[r][c], (_Float16)t[r + 1][c]};
    *(half2v*)(dst + (size_t)(cb + c) * R + rb + r) = p;
  }
}

// ------- router pass 1: logits, softmax, top2 -> topE/wcomb, block partials --
__global__ __launch_bounds__(256) void k_route1(
    const float* __restrict__ x, const float* __restrict__ rw,
    int* __restrict__ topE, float* __restrict__ wcomb, float* __restrict__ blk) {
  __shared__ float s_imp[NEXP];
  __shared__ float s_z;
  int tid = threadIdx.x;
  if (tid < NEXP) s_imp[tid] = 0.f;
  if (tid == 0) s_z = 0.f;
  __syncthreads();
  int wave = tid >> 6, lane = tid & 63;
  int n = blockIdx.x * 4 + wave;
  const float* xr = x + (size_t)n * D_MODEL;
  float acc[8] = {0, 0, 0, 0, 0, 0, 0, 0};
  float4 v0 = *(const float4*)(xr + lane * 8);
  float4 v1 = *(const float4*)(xr + lane * 8 + 4);
  float xs[8] = {v0.x, v0.y, v0.z, v0.w, v1.x, v1.y, v1.z, v1.w};
#pragma unroll
  for (int j = 0; j < 8; j++) {
    const float4* w4 = (const float4*)(rw + (size_t)(lane * 8 + j) * NEXP);
    float4 wa = w4[0], wb = w4[1];
    acc[0] += xs[j] * wa.x; acc[1] += xs[j] * wa.y;
    acc[2] += xs[j] * wa.z; acc[3] += xs[j] * wa.w;
    acc[4] += xs[j] * wb.x; acc[5] += xs[j] * wb.y;
    acc[6] += xs[j] * wb.z; acc[7] += xs[j] * wb.w;
  }
#pragma unroll
  for (int off = 32; off >= 1; off >>= 1) {
#pragma unroll
    for (int e = 0; e < 8; e++) acc[e] += __shfl_xor(acc[e], off);
  }
  if (lane == 0) {
    float z = 0.f;
#pragma unroll
    for (int e = 0; e < 8; e++) z += acc[e] * acc[e];
    float m = acc[0];
#pragma unroll
    for (int e = 1; e < 8; e++) m = fmaxf(m, acc[e]);
    float p[8], s = 0.f;
#pragma unroll
    for (int e = 0; e < 8; e++) { p[e] = expf(acc[e] - m); s += p[e]; }
    float inv = 1.f / s;
#pragma unroll
    for (int e = 0; e < 8; e++) p[e] *= inv;
    int e0 = 0; float p0 = p[0];
#pragma unroll
    for (int e = 1; e < 8; e++) if (p[e] > p0) { p0 = p[e]; e0 = e; }
    int e1 = -1; float p1 = -1.f;
#pragma unroll
    for (int e = 0; e < 8; e++) if (e != e0 && p[e] > p1) { p1 = p[e]; e1 = e; }
    float wsum = p0 + p1;
    topE[n] = e0 | (e1 << 4);
    wcomb[2 * n] = p0 / wsum;
    wcomb[2 * n + 1] = p1 / wsum;
#pragma unroll
    for (int e = 0; e < 8; e++) atomicAdd(&s_imp[e], p[e]);
    atomicAdd(&s_z, z);
  }
  __syncthreads();
  if (tid < 8) blk[blockIdx.x * 9 + tid] = s_imp[tid];
  if (tid == 8) blk[blockIdx.x * 9 + 8] = s_z;
}

// ------- router pass 2 (1 block): build lists + cnt + pad, losses ------------
__global__ __launch_bounds__(1024) void k_scatter(
    const int* __restrict__ topE, const float* __restrict__ blk,
    int* __restrict__ lists, int* __restrict__ cnt, float* __restrict__ out) {
  __shared__ int wcount[16][8];
  __shared__ int gbase[8];
  __shared__ int loadc[8];
  __shared__ float fin[9];
  int tid = threadIdx.x, lane = tid & 63, wv = tid >> 6;
  if (tid < 8) { gbase[tid] = 0; loadc[tid] = 0; }
  __syncthreads();
  for (int c = 0; c < 8; c++) {
    int idx = c * 1024 + tid;
    int te = topE[idx >> 1];
    int e = (idx & 1) ? ((te >> 4) & 15) : (te & 15);
    unsigned long long bal[8], bload[8];
#pragma unroll
    for (int k = 0; k < 8; k++) bal[k] = __ballot(e == k);
#pragma unroll
    for (int k = 0; k < 8; k++) bload[k] = __ballot(e == k && !(tid & 1));
    int rank = __popcll(bal[e] & ((1ull << lane) - 1));
    if (lane < 8) {
      wcount[wv][lane] = __popcll(bal[lane]);
      atomicAdd(&loadc[lane], __popcll(bload[lane]));
    }
    __syncthreads();
    int pre = 0;
    for (int w2 = 0; w2 < wv; w2++) pre += wcount[w2][e];
    int pos = gbase[e] + pre + rank;
    lists[e * LSTRIDE + pos] = idx;
    __syncthreads();
    if (tid < 8) {
      int tot = 0;
#pragma unroll
      for (int w2 = 0; w2 < 16; w2++) tot += wcount[w2][tid];
      gbase[tid] += tot;
    }
    __syncthreads();
  }
  if (tid < 8) cnt[tid] = gbase[tid];
  __syncthreads();
  // pad each expert's list to the next multiple of 128 with DUMMY
  for (int i = tid; i < 8 * 128; i += 1024) {
    int e = i >> 7;
    int p = gbase[e] + (i & 127);
    int lim = (gbase[e] + 127) & ~127;
    if (p < lim) lists[e * LSTRIDE + p] = DUMMY;
  }
  // loss reduction: fin[j] = sum over 1024 blocks of blk[b][j]
  if (wv < 9) {
    float s = 0.f;
    for (int b = lane; b < 1024; b += 64) s += blk[b * 9 + wv];
#pragma unroll
    for (int off = 32; off >= 1; off >>= 1) s += __shfl_xor(s, off);
    if (lane == 0) fin[wv] = s;
  }
  __syncthreads();
  if (tid == 0) {
    float a = 0.f;
#pragma unroll
    for (int e = 0; e < 8; e++)
      a += (fin[e] * (1.f / 4096.f)) * ((float)loadc[e] * (1.f / 4096.f));
    out[NTOK * D_MODEL] = 8.f * a * 0.01f;
    out[NTOK * D_MODEL + 1] = fin[8] * (1.f / (4096.f * 8.f)) * 1e-4f;
  }
}

// ---------------- gemm1: h[pair] = silu(x@w1) * (x@w3), f16 out --------------
__global__ __launch_bounds__(256) void k_gemm1(
    const _Float16* __restrict__ xb, const _Float16* __restrict__ w1t,
    const _Float16* __restrict__ w3t, _Float16* __restrict__ h,
    const int* __restrict__ lists, const int* __restrict__ cnt) {
  int e = blockIdx.z, mt = blockIdx.y, nt = blockIdx.x;
  if (mt * 128 >= cnt[e]) return;
  __shared__ __align__(16) _Float16 As[128 * 64];
  __shared__ __align__(16) _Float16 B1s[128 * 64];
  __shared__ __align__(16) _Float16 B3s[128 * 64];
  __shared__ int toks[128];
  int tid = threadIdx.x, lane = tid & 63, w = tid >> 6;
  if (tid < 128) toks[tid] = lists[e * LSTRIDE + mt * 128 + tid];
  __syncthreads();
  const _Float16* w1e = w1t + (size_t)e * D_FF * D_MODEL;
  const _Float16* w3e = w3t + (size_t)e * D_FF * D_MODEL;
  int n0 = nt * 128;
  const _Float16 *aS[4], *b1S[4], *b3S[4];
#pragma unroll
  for (int c = 0; c < 4; c++) {
    int rt = w * 32 + c * 8 + (lane >> 3);
    int ch = (lane & 7) ^ (rt & 7);
    aS[c] = xb + (size_t)(toks[rt] >> 1) * D_MODEL + ch * 8;
    b1S[c] = w1e + (size_t)(n0 + rt) * D_MODEL + ch * 8;
    b3S[c] = w3e + (size_t)(n0 + rt) * D_MODEL + ch * 8;
  }
  f32x4 acc1[4][4] = {};
  f32x4 acc3[4][4] = {};
  int wr = (w >> 1) * 64, wc = (w & 1) * 64;
  for (int k0 = 0; k0 < D_MODEL; k0 += 64) {
#pragma unroll
    for (int c = 0; c < 4; c++) {
      int rb = (w * 32 + c * 8) * 64;
      gload16(aS[c] + k0, As + rb);
      gload16(b1S[c] + k0, B1s + rb);
      gload16(b3S[c] + k0, B3s + rb);
    }
    __syncthreads();
#pragma unroll
    for (int s = 0; s < 2; s++) {
      int cidx = s * 4 + (lane >> 4);
      half8 af[4], b1f[4], b3f[4];
#pragma unroll
      for (int i = 0; i < 4; i++) {
        int r = wr + i * 16 + (lane & 15);
        af[i] = *(const half8*)(As + r * 64 + ((cidx ^ (r & 7)) << 3));
      }
#pragma unroll
      for (int j = 0; j < 4; j++) {
        int r = wc + j * 16 + (lane & 15);
        int off = r * 64 + ((cidx ^ (r & 7)) << 3);
        b1f[j] = *(const half8*)(B1s + off);
        b3f[j] = *(const half8*)(B3s + off);
      }
#pragma unroll
      for (int i = 0; i < 4; i++) {
#pragma unroll
        for (int j = 0; j < 4; j++) {
          acc1[i][j] = __builtin_amdgcn_mfma_f32_16x16x32_f16(af[i], b1f[j], acc1[i][j], 0, 0, 0);
          acc3[i][j] = __builtin_amdgcn_mfma_f32_16x16x32_f16(af[i], b3f[j], acc3[i][j], 0, 0, 0);
        }
      }
    }
    __syncthreads();
  }
#pragma unroll
  for (int i = 0; i < 4; i++) {
    int rbase = wr + i * 16 + ((lane >> 4) << 2);
#pragma unroll
    for (int r = 0; r < 4; r++) {
      int m = rbase + r;
      int pair = toks[m];
      _Float16* hrow = h + (size_t)pair * D_FF + n0 + wc;
#pragma unroll
      for (int j = 0; j < 4; j++) {
        float g = acc1[i][j][r], u = acc3[i][j][r];
        float val = (g / (1.f + __expf(-g))) * u;
        hrow[j * 16 + (lane & 15)] = (_Float16)val;
      }
    }
  }
}

// ---------------- gemm2: pairout[pair] = h[pair] @ w2 (f32, no atomics) ------
__global__ __launch_bounds__(256) void k_gemm2(
    const _Float16* __restrict__ h, const _Float16* __restrict__ w2t,
    float* __restrict__ pairout, const int* __restrict__ lists,
    const int* __restrict__ cnt) {
  int e = blockIdx.z, mt = blockIdx.y, nt = blockIdx.x;
  if (mt * 128 >= cnt[e]) return;
  __shared__ __align__(16) _Float16 As[128 * 64];
  __shared__ __align__(16) _Float16 Bs[64 * 64];
  __shared__ int toks[128];
  int tid = threadIdx.x, lane = tid & 63, w = tid >> 6;
  if (tid < 128) toks[tid] = lists[e * LSTRIDE + mt * 128 + tid];
  __syncthreads();
  const _Float16* w2e = w2t + (size_t)e * D_MODEL * D_FF;
  int n0 = nt * 64;
  const _Float16 *aS[4], *bS[2];
#pragma unroll
  for (int c = 0; c < 4; c++) {
    int rt = w * 32 + c * 8 + (lane >> 3);
    int ch = (lane & 7) ^ (rt & 7);
    aS[c] = h + (size_t)toks[rt] * D_FF + ch * 8;
  }
#pragma unroll
  for (int c = 0; c < 2; c++) {
    int rt = w * 16 + c * 8 + (lane >> 3);
    int ch = (lane & 7) ^ (rt & 7);
    bS[c] = w2e + (size_t)(n0 + rt) * D_FF + ch * 8;
  }
  f32x4 acc[4][2] = {};
  int wr = (w >> 1) * 64, wc = (w & 1) * 32;
  for (int k0 = 0; k0 < D_FF; k0 += 64) {
#pragma unroll
    for (int c = 0; c < 4; c++) gload16(aS[c] + k0, As + (w * 32 + c * 8) * 64);
#pragma unroll
    for (int c = 0; c < 2; c++) gload16(bS[c] + k0, Bs + (w * 16 + c * 8) * 64);
    __syncthreads();
#pragma unroll
    for (int s = 0; s < 2; s++) {
      int cidx = s * 4 + (lane >> 4);
      half8 af[4], bf[2];
#pragma unroll
      for (int i = 0; i < 4; i++) {
        int r = wr + i * 16 + (lane & 15);
        af[i] = *(const half8*)(As + r * 64 + ((cidx ^ (r & 7)) << 3));
      }
#pragma unroll
      for (int j = 0; j < 2; j++) {
        int r = wc + j * 16 + (lane & 15);
        bf[j] = *(const half8*)(Bs + r * 64 + ((cidx ^ (r & 7)) << 3));
      }
#pragma unroll
      for (int i = 0; i < 4; i++) {
#pragma unroll
        for (int j = 0; j < 2; j++)
          acc[i][j] = __builtin_amdgcn_mfma_f32_16x16x32_f16(af[i], bf[j], acc[i][j], 0, 0, 0);
      }
    }
    __syncthreads();
  }
#pragma unroll
  for (int i = 0; i < 4; i++) {
    int rbase = wr + i * 16 + ((lane >> 4) << 2);
#pragma unroll
    for (int r = 0; r < 4; r++) {
      int m = rbase + r;
      int pair = toks[m];
      float* orow = pairout + (size_t)pair * D_MODEL + n0 + wc;
#pragma unroll
      for (int j = 0; j < 2; j++)
        orow[j * 16 + (lane & 15)] = acc[i][j][r];
    }
  }
}

// ---------------- combine: out[n] = w0*po[2n] + w1*po[2n+1] ------------------
__global__ void k_combine(const float* __restrict__ po, const float* __restrict__ wcomb,
                          float* __restrict__ out) {
  int gid = blockIdx.x * blockDim.x + threadIdx.x;
  int r = gid >> 7;
  int c = (gid & 127) * 4;
  float w0 = wcomb[2 * r], w1 = wcomb[2 * r + 1];
  const float4 a = *(const float4*)(po + (size_t)(2 * r) * D_MODEL + c);
  const float4 b = *(const float4*)(po + (size_t)(2 * r + 1) * D_MODEL + c);
  float4 o{w0 * a.x + w1 * b.x, w0 * a.y + w1 * b.y,
           w0 * a.z + w1 * b.z, w0 * a.w + w1 * b.w};
  *(float4*)(out + (size_t)r * D_MODEL + c) = o;
}

extern "C" void kernel_launch(void* const* d_in, const int* in_sizes, int n_in,
                              void* d_out, int out_size, void* d_ws, size_t ws_size,
                              hipStream_t stream) {
  const float* x = (const float*)d_in[0];
  const float* rw = (const float*)d_in[1];
  const float* w1 = (const float*)d_in[2];
  const float* w2 = (const float*)d_in[3];
  const float* w3 = (const float*)d_in[4];
  float* out = (float*)d_out;

  char* ws = (char*)d_ws;
  size_t o = 0;
  _Float16* w1t = (_Float16*)(ws + o); o += (size_t)NEXP * D_FF * D_MODEL * 2;
  _Float16* w3t = (_Float16*)(ws + o); o += (size_t)NEXP * D_FF * D_MODEL * 2;
  _Float16* w2t = (_Float16*)(ws + o); o += (size_t)NEXP * D_MODEL * D_FF * 2;
  _Float16* xb = (_Float16*)(ws + o); o += (size_t)(NTOK + 1) * D_MODEL * 2;
  _Float16* hbuf = (_Float16*)(ws + o); o += (size_t)(NPAIR + 1) * D_FF * 2;
  int* lists = (int*)(ws + o); o += (size_t)NEXP * LSTRIDE * 4;
  float* wcomb = (float*)(ws + o); o += (size_t)NPAIR * 4;
  int* topE = (int*)(ws + o); o += (size_t)NTOK * 4;
  float* blk = (float*)(ws + o); o += (size_t)1024 * 9 * 4;
  int* cnt = (int*)(ws + o); o += 128;
  // pairout aliases the w1t/w3t region (dead after gemm1, gemm2 runs later)
  float* pairout = (float*)ws;  // needs (NPAIR+1)*D_MODEL*4 = 16.78MB < 33.5MB
  if (ws_size < o) return;  // workspace too small — refuse to corrupt

  k_cvtx<<<(NTOK * D_MODEL / 8 + 255) / 256, 256, 0, stream>>>(x, xb);
  k_trans3<<<6144, 256, 0, stream>>>(w1, w3, w2, w1t, w3t, w2t);
  k_route1<<<NTOK / 4, 256, 0, stream>>>(x, rw, topE, wcomb, blk);
  k_scatter<<<1, 1024, 0, stream>>>(topE, blk, lists, cnt, out);
  k_gemm1<<<dim3(D_FF / 128, 32, NEXP), 256, 0, stream>>>(xb, w1t, w3t, hbuf, lists, cnt);
  k_gemm2<<<dim3(D_MODEL / 64, 32, NEXP), 256, 0, stream>>>(hbuf, w2t, pairout, lists, cnt);
  k_combine<<<(NTOK * D_MODEL / 4 + 255) / 256, 256, 0, stream>>>(pairout, wcomb, out);
}

// Round 4
// 299.867 us; speedup vs baseline: 1.3776x; 1.0594x over previous
//
#include <hip/hip_runtime.h>
#include <hip/hip_fp16.h>

#define D_MODEL 512
#define D_FF    2048
#define NEXP    8
#define NTOK    4096
#define NPAIR   8192
#define DUMMY   NPAIR
#define LSTRIDE 4224   // 4096 + 128 pad
#define MAXTILES 72

typedef _Float16 half8  __attribute__((ext_vector_type(8)));
typedef _Float16 half2v __attribute__((ext_vector_type(2)));
typedef float    f32x4  __attribute__((ext_vector_type(4)));

__device__ __forceinline__ void gload16(const void* g, void* l) {
  __builtin_amdgcn_global_load_lds(
      (const __attribute__((address_space(1))) unsigned*)g,
      (__attribute__((address_space(3))) unsigned*)l, 16, 0, 0);
}

// ------------- merged transpose+convert for w1,w3,w2: [R][C]f32 -> [C][R]f16 -
__global__ void k_trans3(const float* __restrict__ w1, const float* __restrict__ w3,
                         const float* __restrict__ w2, _Float16* __restrict__ w1t,
                         _Float16* __restrict__ w3t, _Float16* __restrict__ w2t) {
  __shared__ float t[64][65];
  int bt = blockIdx.x;
  const float* src; _Float16* dst; int R, C, rb, cb;
  if (bt < 4096) {
    src = (bt < 2048) ? w1 : w3; dst = (bt < 2048) ? w1t : w3t;
    int tt = bt & 2047; int e = tt >> 8; int rem = tt & 255;
    R = D_MODEL; C = D_FF; rb = (rem >> 5) * 64; cb = (rem & 31) * 64;
    src += (size_t)e * R * C; dst += (size_t)e * R * C;
  } else {
    int tt = bt - 4096; int e = tt >> 8; int rem = tt & 255;
    src = w2; dst = w2t;
    R = D_FF; C = D_MODEL; rb = (rem >> 3) * 64; cb = (rem & 7) * 64;
    src += (size_t)e * R * C; dst += (size_t)e * R * C;
  }
  int tid = threadIdx.x;
  int tx = tid & 15, ty = tid >> 4;
#pragma unroll
  for (int i = 0; i < 4; i++) {
    float4 v = *(const float4*)(src + (size_t)(rb + ty + i * 16) * C + cb + tx * 4);
    t[ty + i * 16][tx * 4 + 0] = v.x;
    t[ty + i * 16][tx * 4 + 1] = v.y;
    t[ty + i * 16][tx * 4 + 2] = v.z;
    t[ty + i * 16][tx * 4 + 3] = v.w;
  }
  __syncthreads();
  int tx2 = tid & 31, ty2 = tid >> 5;
#pragma unroll
  for (int i = 0; i < 8; i++) {
    int c = ty2 + i * 8;
    int r = tx2 * 2;
    half2v p = {(_Float16)t[r][c], (_Float16)t[r + 1][c]};
    *(half2v*)(dst + (size_t)(cb + c) * R + rb + r) = p;
  }
}

// ------- router pass 1: logits, softmax, top2; also emits xb (f16 x) ---------
__global__ __launch_bounds__(256) void k_route1(
    const float* __restrict__ x, const float* __restrict__ rw,
    _Float16* __restrict__ xb, int* __restrict__ topE, float* __restrict__ wcomb,
    float* __restrict__ blk, int* __restrict__ ntiles) {
  __shared__ float s_imp[NEXP];
  __shared__ float s_z;
  int tid = threadIdx.x;
  if (tid < NEXP) s_imp[tid] = 0.f;
  if (tid == 0) s_z = 0.f;
  if (blockIdx.x == 0 && tid == 0) ntiles[0] = 0;
  __syncthreads();
  int wave = tid >> 6, lane = tid & 63;
  int n = blockIdx.x * 4 + wave;
  const float* xr = x + (size_t)n * D_MODEL;
  float acc[8] = {0, 0, 0, 0, 0, 0, 0, 0};
  float4 v0 = *(const float4*)(xr + lane * 8);
  float4 v1 = *(const float4*)(xr + lane * 8 + 4);
  float xs[8] = {v0.x, v0.y, v0.z, v0.w, v1.x, v1.y, v1.z, v1.w};
  // fused f16 conversion of x
  half8 hx = {(_Float16)xs[0], (_Float16)xs[1], (_Float16)xs[2], (_Float16)xs[3],
              (_Float16)xs[4], (_Float16)xs[5], (_Float16)xs[6], (_Float16)xs[7]};
  *(half8*)(xb + (size_t)n * D_MODEL + lane * 8) = hx;
#pragma unroll
  for (int j = 0; j < 8; j++) {
    const float4* w4 = (const float4*)(rw + (size_t)(lane * 8 + j) * NEXP);
    float4 wa = w4[0], wb = w4[1];
    acc[0] += xs[j] * wa.x; acc[1] += xs[j] * wa.y;
    acc[2] += xs[j] * wa.z; acc[3] += xs[j] * wa.w;
    acc[4] += xs[j] * wb.x; acc[5] += xs[j] * wb.y;
    acc[6] += xs[j] * wb.z; acc[7] += xs[j] * wb.w;
  }
#pragma unroll
  for (int off = 32; off >= 1; off >>= 1) {
#pragma unroll
    for (int e = 0; e < 8; e++) acc[e] += __shfl_xor(acc[e], off);
  }
  if (lane == 0) {
    float z = 0.f;
#pragma unroll
    for (int e = 0; e < 8; e++) z += acc[e] * acc[e];
    float m = acc[0];
#pragma unroll
    for (int e = 1; e < 8; e++) m = fmaxf(m, acc[e]);
    float p[8], s = 0.f;
#pragma unroll
    for (int e = 0; e < 8; e++) { p[e] = expf(acc[e] - m); s += p[e]; }
    float inv = 1.f / s;
#pragma unroll
    for (int e = 0; e < 8; e++) p[e] *= inv;
    int e0 = 0; float p0 = p[0];
#pragma unroll
    for (int e = 1; e < 8; e++) if (p[e] > p0) { p0 = p[e]; e0 = e; }
    int e1 = -1; float p1 = -1.f;
#pragma unroll
    for (int e = 0; e < 8; e++) if (e != e0 && p[e] > p1) { p1 = p[e]; e1 = e; }
    float wsum = p0 + p1;
    topE[n] = e0 | (e1 << 4);
    wcomb[2 * n] = p0 / wsum;
    wcomb[2 * n + 1] = p1 / wsum;
#pragma unroll
    for (int e = 0; e < 8; e++) atomicAdd(&s_imp[e], p[e]);
    atomicAdd(&s_z, z);
  }
  __syncthreads();
  if (tid < 8) blk[blockIdx.x * 9 + tid] = s_imp[tid];
  if (tid == 8) blk[blockIdx.x * 9 + 8] = s_z;
}

// ------- scatter: 8 blocks (1/expert): build list, pad, tile table, load -----
__global__ __launch_bounds__(1024) void k_scatter(
    const int* __restrict__ topE, int* __restrict__ lists,
    int* __restrict__ tiletab, int* __restrict__ ntiles,
    int* __restrict__ loadc_g) {
  int e = blockIdx.x;
  __shared__ int wcount[16];
  __shared__ int lcw[16];
  __shared__ int sbase;
  __shared__ int stot;
  int tid = threadIdx.x, lane = tid & 63, wv = tid >> 6;
  if (lane == 0) lcw[wv] = 0;
  int total = 0;
  for (int c = 0; c < 8; c++) {
    int idx = c * 1024 + tid;
    int te = topE[idx >> 1];
    int ee = (idx & 1) ? ((te >> 4) & 15) : (te & 15);
    bool mine = (ee == e);
    unsigned long long bal = __ballot(mine);
    unsigned long long balL = __ballot(mine && !(idx & 1));  // convergent: all lanes
    int rank = __popcll(bal & ((1ull << lane) - 1ull));
    if (lane == 0) {
      wcount[wv] = __popcll(bal);
      lcw[wv] += __popcll(balL);
    }
    __syncthreads();
    int pre = total;
    for (int w2 = 0; w2 < wv; w2++) pre += wcount[w2];
    if (mine) lists[e * LSTRIDE + pre + rank] = idx;
    int t16 = 0;
#pragma unroll
    for (int w2 = 0; w2 < 16; w2++) t16 += wcount[w2];
    __syncthreads();
    total += t16;
  }
  int tiles = (total + 127) >> 7;
  if (tid == 0) {
    int lc = 0;
#pragma unroll
    for (int w2 = 0; w2 < 16; w2++) lc += lcw[w2];
    loadc_g[e] = lc;
    sbase = atomicAdd(ntiles, tiles);
    stot = total;
  }
  __syncthreads();
  if (tid < tiles) tiletab[sbase + tid] = e | (tid << 8);
  if (tid < 128) {
    int p = stot + tid;
    if (p < tiles * 128) lists[e * LSTRIDE + p] = DUMMY;
  }
}

// ---------------- losses ----------------
__global__ __launch_bounds__(1024) void k_losses(
    const float* __restrict__ blk, const int* __restrict__ loadc_g,
    float* __restrict__ out) {
  __shared__ float fin[9];
  int tid = threadIdx.x, lane = tid & 63, wv = tid >> 6;
  if (wv < 9) {
    float s = 0.f;
    for (int b = lane; b < 1024; b += 64) s += blk[b * 9 + wv];
#pragma unroll
    for (int off = 32; off >= 1; off >>= 1) s += __shfl_xor(s, off);
    if (lane == 0) fin[wv] = s;
  }
  __syncthreads();
  if (tid == 0) {
    float a = 0.f;
#pragma unroll
    for (int e = 0; e < 8; e++)
      a += (fin[e] * (1.f / 4096.f)) * ((float)loadc_g[e] * (1.f / 4096.f));
    out[NTOK * D_MODEL] = 8.f * a * 0.01f;
    out[NTOK * D_MODEL + 1] = fin[8] * (1.f / (4096.f * 8.f)) * 1e-4f;
  }
}

// -------- gemm1: h[pair] = silu(x@w1)*(x@w3); 128x128, BK=32, 2-phase dbuf ---
__global__ __launch_bounds__(256) void k_gemm1(
    const _Float16* __restrict__ xb, const _Float16* __restrict__ w1t,
    const _Float16* __restrict__ w3t, _Float16* __restrict__ h,
    const int* __restrict__ lists, const int* __restrict__ tiletab,
    const int* __restrict__ ntiles) {
  int ti = blockIdx.y;
  if (ti >= ntiles[0]) return;
  int ent = tiletab[ti];
  int e = ent & 15, mt = ent >> 8, nt = blockIdx.x;
  __shared__ __align__(16) _Float16 As[2][128 * 32];
  __shared__ __align__(16) _Float16 B1s[2][128 * 32];
  __shared__ __align__(16) _Float16 B3s[2][128 * 32];
  __shared__ int toks[128];
  int tid = threadIdx.x, lane = tid & 63, w = tid >> 6;
  if (tid < 128) toks[tid] = lists[e * LSTRIDE + mt * 128 + tid];
  __syncthreads();
  const _Float16* w1e = w1t + (size_t)e * D_FF * D_MODEL;
  const _Float16* w3e = w3t + (size_t)e * D_FF * D_MODEL;
  int n0 = nt * 128;
  const _Float16 *aS[2], *b1S[2], *b3S[2];
  int ldso[2];
#pragma unroll
  for (int c = 0; c < 2; c++) {
    int rt = w * 32 + c * 16 + (lane >> 2);
    int cg = (lane & 3) ^ ((rt >> 1) & 3);
    aS[c] = xb + (size_t)(toks[rt] >> 1) * D_MODEL + cg * 8;
    b1S[c] = w1e + (size_t)(n0 + rt) * D_MODEL + cg * 8;
    b3S[c] = w3e + (size_t)(n0 + rt) * D_MODEL + cg * 8;
    ldso[c] = (w * 32 + c * 16) * 32;
  }
  f32x4 acc1[4][4] = {};
  f32x4 acc3[4][4] = {};
  int wr = (w >> 1) * 64, wc = (w & 1) * 64;
  int aoff[4], boff[4];
#pragma unroll
  for (int i = 0; i < 4; i++) {
    int r = wr + i * 16 + (lane & 15);
    aoff[i] = r * 32 + (((lane >> 4) ^ ((r >> 1) & 3)) << 3);
    int rb = wc + i * 16 + (lane & 15);
    boff[i] = rb * 32 + (((lane >> 4) ^ ((rb >> 1) & 3)) << 3);
  }
#pragma unroll
  for (int c = 0; c < 2; c++) {
    gload16(aS[c], &As[0][ldso[c]]);
    gload16(b1S[c], &B1s[0][ldso[c]]);
    gload16(b3S[c], &B3s[0][ldso[c]]);
  }
  __syncthreads();
#pragma unroll
  for (int t = 0; t < 16; t++) {
    const int buf = t & 1;
    if (t < 15) {
      const int k1 = (t + 1) * 32;
#pragma unroll
      for (int c = 0; c < 2; c++) {
        gload16(aS[c] + k1, &As[buf ^ 1][ldso[c]]);
        gload16(b1S[c] + k1, &B1s[buf ^ 1][ldso[c]]);
        gload16(b3S[c] + k1, &B3s[buf ^ 1][ldso[c]]);
      }
    }
    half8 af[4], b1f[4], b3f[4];
#pragma unroll
    for (int i = 0; i < 4; i++) {
      af[i] = *(const half8*)(&As[buf][aoff[i]]);
      b1f[i] = *(const half8*)(&B1s[buf][boff[i]]);
      b3f[i] = *(const half8*)(&B3s[buf][boff[i]]);
    }
#pragma unroll
    for (int i = 0; i < 4; i++) {
#pragma unroll
      for (int j = 0; j < 4; j++) {
        acc1[i][j] = __builtin_amdgcn_mfma_f32_16x16x32_f16(af[i], b1f[j], acc1[i][j], 0, 0, 0);
        acc3[i][j] = __builtin_amdgcn_mfma_f32_16x16x32_f16(af[i], b3f[j], acc3[i][j], 0, 0, 0);
      }
    }
    __syncthreads();
  }
#pragma unroll
  for (int i = 0; i < 4; i++) {
    int rbase = wr + i * 16 + ((lane >> 4) << 2);
#pragma unroll
    for (int r = 0; r < 4; r++) {
      int m = rbase + r;
      int pair = toks[m];
      _Float16* hrow = h + (size_t)pair * D_FF + n0 + wc;
#pragma unroll
      for (int j = 0; j < 4; j++) {
        float g = acc1[i][j][r], u = acc3[i][j][r];
        float val = (g / (1.f + __expf(-g))) * u;
        hrow[j * 16 + (lane & 15)] = (_Float16)val;
      }
    }
  }
}

// -------- gemm2: pairout[pair] = wc*(h[pair]@w2); 128x64, BK=32, 2-phase -----
__global__ __launch_bounds__(256) void k_gemm2(
    const _Float16* __restrict__ h, const _Float16* __restrict__ w2t,
    float* __restrict__ pairout, const int* __restrict__ lists,
    const int* __restrict__ tiletab, const int* __restrict__ ntiles,
    const float* __restrict__ wcomb) {
  int ti = blockIdx.y;
  if (ti >= ntiles[0]) return;
  int ent = tiletab[ti];
  int e = ent & 15, mt = ent >> 8, nt = blockIdx.x;
  __shared__ __align__(16) _Float16 As[2][128 * 32];
  __shared__ __align__(16) _Float16 Bs[2][64 * 32];
  __shared__ int toks[128];
  __shared__ float wcs[128];
  int tid = threadIdx.x, lane = tid & 63, w = tid >> 6;
  if (tid < 128) {
    int p = lists[e * LSTRIDE + mt * 128 + tid];
    toks[tid] = p;
    wcs[tid] = (p < NPAIR) ? wcomb[p] : 0.f;
  }
  __syncthreads();
  const _Float16* w2e = w2t + (size_t)e * D_MODEL * D_FF;
  int n0 = nt * 64;
  const _Float16 *aS[2], *bS;
  int ldsa[2], ldsb;
#pragma unroll
  for (int c = 0; c < 2; c++) {
    int rt = w * 32 + c * 16 + (lane >> 2);
    int cg = (lane & 3) ^ ((rt >> 1) & 3);
    aS[c] = h + (size_t)toks[rt] * D_FF + cg * 8;
    ldsa[c] = (w * 32 + c * 16) * 32;
  }
  {
    int rt = w * 16 + (lane >> 2);
    int cg = (lane & 3) ^ ((rt >> 1) & 3);
    bS = w2e + (size_t)(n0 + rt) * D_FF + cg * 8;
    ldsb = (w * 16) * 32;
  }
  f32x4 acc[4][2] = {};
  int wr = (w >> 1) * 64, wc = (w & 1) * 32;
  int aoff[4], boff[2];
#pragma unroll
  for (int i = 0; i < 4; i++) {
    int r = wr + i * 16 + (lane & 15);
    aoff[i] = r * 32 + (((lane >> 4) ^ ((r >> 1) & 3)) << 3);
  }
#pragma unroll
  for (int j = 0; j < 2; j++) {
    int r = wc + j * 16 + (lane & 15);
    boff[j] = r * 32 + (((lane >> 4) ^ ((r >> 1) & 3)) << 3);
  }
  // prologue: stage k=0 into buf0
#pragma unroll
  for (int c = 0; c < 2; c++) gload16(aS[c], &As[0][ldsa[c]]);
  gload16(bS, &Bs[0][ldsb]);
  __syncthreads();
  for (int kk = 0; kk < D_FF; kk += 64) {
    // step A: stage kk+32 -> buf1, compute buf0
    {
#pragma unroll
      for (int c = 0; c < 2; c++) gload16(aS[c] + kk + 32, &As[1][ldsa[c]]);
      gload16(bS + kk + 32, &Bs[1][ldsb]);
      half8 af[4], bf[2];
#pragma unroll
      for (int i = 0; i < 4; i++) af[i] = *(const half8*)(&As[0][aoff[i]]);
#pragma unroll
      for (int j = 0; j < 2; j++) bf[j] = *(const half8*)(&Bs[0][boff[j]]);
#pragma unroll
      for (int i = 0; i < 4; i++)
#pragma unroll
        for (int j = 0; j < 2; j++)
          acc[i][j] = __builtin_amdgcn_mfma_f32_16x16x32_f16(af[i], bf[j], acc[i][j], 0, 0, 0);
      __syncthreads();
    }
    // step B: stage kk+64 -> buf0 (unless last), compute buf1
    {
      if (kk + 64 < D_FF) {
#pragma unroll
        for (int c = 0; c < 2; c++) gload16(aS[c] + kk + 64, &As[0][ldsa[c]]);
        gload16(bS + kk + 64, &Bs[0][ldsb]);
      }
      half8 af[4], bf[2];
#pragma unroll
      for (int i = 0; i < 4; i++) af[i] = *(const half8*)(&As[1][aoff[i]]);
#pragma unroll
      for (int j = 0; j < 2; j++) bf[j] = *(const half8*)(&Bs[1][boff[j]]);
#pragma unroll
      for (int i = 0; i < 4; i++)
#pragma unroll
        for (int j = 0; j < 2; j++)
          acc[i][j] = __builtin_amdgcn_mfma_f32_16x16x32_f16(af[i], bf[j], acc[i][j], 0, 0, 0);
      __syncthreads();
    }
  }
#pragma unroll
  for (int i = 0; i < 4; i++) {
    int rbase = wr + i * 16 + ((lane >> 4) << 2);
#pragma unroll
    for (int r = 0; r < 4; r++) {
      int m = rbase + r;
      int pair = toks[m];
      float wv_ = wcs[m];
      float* orow = pairout + (size_t)pair * D_MODEL + n0 + wc;  // FIX: + wc restored
#pragma unroll
      for (int j = 0; j < 2; j++)
        orow[j * 16 + (lane & 15)] = acc[i][j][r] * wv_;
    }
  }
}

// ---------------- combine: out[n] = po[2n] + po[2n+1] (weights pre-applied) --
__global__ void k_combine(const float* __restrict__ po, float* __restrict__ out) {
  int gid = blockIdx.x * blockDim.x + threadIdx.x;
  int r = gid >> 7;
  int c = (gid & 127) * 4;
  const float4 a = *(const float4*)(po + (size_t)(2 * r) * D_MODEL + c);
  const float4 b = *(const float4*)(po + (size_t)(2 * r + 1) * D_MODEL + c);
  float4 o{a.x + b.x, a.y + b.y, a.z + b.z, a.w + b.w};
  *(float4*)(out + (size_t)r * D_MODEL + c) = o;
}

extern "C" void kernel_launch(void* const* d_in, const int* in_sizes, int n_in,
                              void* d_out, int out_size, void* d_ws, size_t ws_size,
                              hipStream_t stream) {
  const float* x = (const float*)d_in[0];
  const float* rw = (const float*)d_in[1];
  const float* w1 = (const float*)d_in[2];
  const float* w2 = (const float*)d_in[3];
  const float* w3 = (const float*)d_in[4];
  float* out = (float*)d_out;

  char* ws = (char*)d_ws;
  size_t o = 0;
  _Float16* w1t = (_Float16*)(ws + o); o += (size_t)NEXP * D_FF * D_MODEL * 2;
  _Float16* w3t = (_Float16*)(ws + o); o += (size_t)NEXP * D_FF * D_MODEL * 2;
  _Float16* w2t = (_Float16*)(ws + o); o += (size_t)NEXP * D_MODEL * D_FF * 2;
  _Float16* xb = (_Float16*)(ws + o); o += (size_t)(NTOK + 1) * D_MODEL * 2;
  _Float16* hbuf = (_Float16*)(ws + o); o += (size_t)(NPAIR + 1) * D_FF * 2;
  int* lists = (int*)(ws + o); o += (size_t)NEXP * LSTRIDE * 4;
  float* wcomb = (float*)(ws + o); o += (size_t)NPAIR * 4;
  int* topE = (int*)(ws + o); o += (size_t)NTOK * 4;
  float* blk = (float*)(ws + o); o += (size_t)1024 * 9 * 4;
  int* tiletab = (int*)(ws + o); o += MAXTILES * 4;
  int* ntiles = (int*)(ws + o); o += 16;
  int* loadc_g = (int*)(ws + o); o += 64;
  // pairout aliases the w1t/w3t region (dead after gemm1; gemm2 runs later)
  float* pairout = (float*)ws;  // (NPAIR+1)*D_MODEL*4 = 16.8MB < 33.5MB
  if (ws_size < o) return;  // workspace too small — refuse to corrupt

  k_route1<<<NTOK / 4, 256, 0, stream>>>(x, rw, xb, topE, wcomb, blk, ntiles);
  k_trans3<<<6144, 256, 0, stream>>>(w1, w3, w2, w1t, w3t, w2t);
  k_scatter<<<NEXP, 1024, 0, stream>>>(topE, lists, tiletab, ntiles, loadc_g);
  k_losses<<<1, 1024, 0, stream>>>(blk, loadc_g, out);
  k_gemm1<<<dim3(D_FF / 128, MAXTILES), 256, 0, stream>>>(xb, w1t, w3t, hbuf, lists, tiletab, ntiles);
  k_gemm2<<<dim3(D_MODEL / 64, MAXTILES), 256, 0, stream>>>(hbuf, w2t, pairout, lists, tiletab, ntiles, wcomb);
  k_combine<<<(NTOK * D_MODEL / 4 + 255) / 256, 256, 0, stream>>>(pairout, out);
}

// Round 5
// 294.053 us; speedup vs baseline: 1.4048x; 1.0198x over previous
//
#include <hip/hip_runtime.h>
#include <hip/hip_fp16.h>

#define D_MODEL 512
#define D_FF    2048
#define NEXP    8
#define NTOK    4096
#define NPAIR   8192
#define DUMMY   NPAIR
#define LSTRIDE 4224   // 4096 + 128 pad
#define MAXTILES 72

typedef _Float16 half8  __attribute__((ext_vector_type(8)));
typedef _Float16 half2v __attribute__((ext_vector_type(2)));
typedef float    f32x4  __attribute__((ext_vector_type(4)));

__device__ __forceinline__ void gload16(const void* g, void* l) {
  __builtin_amdgcn_global_load_lds(
      (const __attribute__((address_space(1))) unsigned*)g,
      (__attribute__((address_space(3))) unsigned*)l, 16, 0, 0);
}

// wait for all but N outstanding VMEM ops, then workgroup barrier.
// asm memory clobbers fence compiler reordering on both sides.
#define PIPE_BARRIER(N) do { \
  asm volatile("s_waitcnt vmcnt(" #N ")" ::: "memory"); \
  __builtin_amdgcn_s_barrier(); \
  asm volatile("" ::: "memory"); \
} while (0)

// ---- k_prep: blocks [0,6144): weight transpose+cvt; [6144,7168): router ----
__global__ __launch_bounds__(256) void k_prep(
    const float* __restrict__ x, const float* __restrict__ rw,
    const float* __restrict__ w1, const float* __restrict__ w3,
    const float* __restrict__ w2, _Float16* __restrict__ w1t,
    _Float16* __restrict__ w3t, _Float16* __restrict__ w2t,
    _Float16* __restrict__ xb, int* __restrict__ topE,
    float* __restrict__ wcomb, float* __restrict__ blk,
    int* __restrict__ ntiles) {
  __shared__ float t[64][65];
  int tid = threadIdx.x;
  if (blockIdx.x < 6144) {
    // -------- transpose+convert: src [R][C] f32 -> dst [C][R] f16 --------
    int bt = blockIdx.x;
    const float* src; _Float16* dst; int R, C, rb, cb;
    if (bt < 4096) {
      src = (bt < 2048) ? w1 : w3; dst = (bt < 2048) ? w1t : w3t;
      int tt = bt & 2047; int e = tt >> 8; int rem = tt & 255;
      R = D_MODEL; C = D_FF; rb = (rem >> 5) * 64; cb = (rem & 31) * 64;
      src += (size_t)e * R * C; dst += (size_t)e * R * C;
    } else {
      int tt = bt - 4096; int e = tt >> 8; int rem = tt & 255;
      src = w2; dst = w2t;
      R = D_FF; C = D_MODEL; rb = (rem >> 3) * 64; cb = (rem & 7) * 64;
      src += (size_t)e * R * C; dst += (size_t)e * R * C;
    }
    int tx = tid & 15, ty = tid >> 4;
#pragma unroll
    for (int i = 0; i < 4; i++) {
      float4 v = *(const float4*)(src + (size_t)(rb + ty + i * 16) * C + cb + tx * 4);
      t[ty + i * 16][tx * 4 + 0] = v.x;
      t[ty + i * 16][tx * 4 + 1] = v.y;
      t[ty + i * 16][tx * 4 + 2] = v.z;
      t[ty + i * 16][tx * 4 + 3] = v.w;
    }
    __syncthreads();
    int tx2 = tid & 31, ty2 = tid >> 5;
#pragma unroll
    for (int i = 0; i < 8; i++) {
      int c = ty2 + i * 8;
      int r = tx2 * 2;
      half2v p = {(_Float16)t[r][c], (_Float16)t[r + 1][c]};
      *(half2v*)(dst + (size_t)(cb + c) * R + rb + r) = p;
    }
  } else {
    // -------- router: logits, softmax, top2; emits xb (f16 x) --------
    int bx = blockIdx.x - 6144;
    __shared__ float s_imp[NEXP];
    __shared__ float s_z;
    if (tid < NEXP) s_imp[tid] = 0.f;
    if (tid == 0) s_z = 0.f;
    if (bx == 0 && tid == 0) ntiles[0] = 0;
    __syncthreads();
    int wave = tid >> 6, lane = tid & 63;
    int n = bx * 4 + wave;
    const float* xr = x + (size_t)n * D_MODEL;
    float acc[8] = {0, 0, 0, 0, 0, 0, 0, 0};
    float4 v0 = *(const float4*)(xr + lane * 8);
    float4 v1 = *(const float4*)(xr + lane * 8 + 4);
    float xs[8] = {v0.x, v0.y, v0.z, v0.w, v1.x, v1.y, v1.z, v1.w};
    half8 hx = {(_Float16)xs[0], (_Float16)xs[1], (_Float16)xs[2], (_Float16)xs[3],
                (_Float16)xs[4], (_Float16)xs[5], (_Float16)xs[6], (_Float16)xs[7]};
    *(half8*)(xb + (size_t)n * D_MODEL + lane * 8) = hx;
#pragma unroll
    for (int j = 0; j < 8; j++) {
      const float4* w4 = (const float4*)(rw + (size_t)(lane * 8 + j) * NEXP);
      float4 wa = w4[0], wb = w4[1];
      acc[0] += xs[j] * wa.x; acc[1] += xs[j] * wa.y;
      acc[2] += xs[j] * wa.z; acc[3] += xs[j] * wa.w;
      acc[4] += xs[j] * wb.x; acc[5] += xs[j] * wb.y;
      acc[6] += xs[j] * wb.z; acc[7] += xs[j] * wb.w;
    }
#pragma unroll
    for (int off = 32; off >= 1; off >>= 1) {
#pragma unroll
      for (int e = 0; e < 8; e++) acc[e] += __shfl_xor(acc[e], off);
    }
    if (lane == 0) {
      float z = 0.f;
#pragma unroll
      for (int e = 0; e < 8; e++) z += acc[e] * acc[e];
      float m = acc[0];
#pragma unroll
      for (int e = 1; e < 8; e++) m = fmaxf(m, acc[e]);
      float p[8], s = 0.f;
#pragma unroll
      for (int e = 0; e < 8; e++) { p[e] = expf(acc[e] - m); s += p[e]; }
      float inv = 1.f / s;
#pragma unroll
      for (int e = 0; e < 8; e++) p[e] *= inv;
      int e0 = 0; float p0 = p[0];
#pragma unroll
      for (int e = 1; e < 8; e++) if (p[e] > p0) { p0 = p[e]; e0 = e; }
      int e1 = -1; float p1 = -1.f;
#pragma unroll
      for (int e = 0; e < 8; e++) if (e != e0 && p[e] > p1) { p1 = p[e]; e1 = e; }
      float wsum = p0 + p1;
      topE[n] = e0 | (e1 << 4);
      wcomb[2 * n] = p0 / wsum;
      wcomb[2 * n + 1] = p1 / wsum;
#pragma unroll
      for (int e = 0; e < 8; e++) atomicAdd(&s_imp[e], p[e]);
      atomicAdd(&s_z, z);
    }
    __syncthreads();
    if (tid < 8) blk[bx * 9 + tid] = s_imp[tid];
    if (tid == 8) blk[bx * 9 + 8] = s_z;
  }
}

// ------- scatter: 8 blocks (1/expert): build list, pad, tile table, load -----
__global__ __launch_bounds__(1024) void k_scatter(
    const int* __restrict__ topE, int* __restrict__ lists,
    int* __restrict__ tiletab, int* __restrict__ ntiles,
    int* __restrict__ loadc_g) {
  int e = blockIdx.x;
  __shared__ int wcount[16];
  __shared__ int lcw[16];
  __shared__ int sbase;
  __shared__ int stot;
  int tid = threadIdx.x, lane = tid & 63, wv = tid >> 6;
  if (lane == 0) lcw[wv] = 0;
  int total = 0;
  for (int c = 0; c < 8; c++) {
    int idx = c * 1024 + tid;
    int te = topE[idx >> 1];
    int ee = (idx & 1) ? ((te >> 4) & 15) : (te & 15);
    bool mine = (ee == e);
    unsigned long long bal = __ballot(mine);
    unsigned long long balL = __ballot(mine && !(idx & 1));  // convergent
    int rank = __popcll(bal & ((1ull << lane) - 1ull));
    if (lane == 0) {
      wcount[wv] = __popcll(bal);
      lcw[wv] += __popcll(balL);
    }
    __syncthreads();
    int pre = total;
    for (int w2 = 0; w2 < wv; w2++) pre += wcount[w2];
    if (mine) lists[e * LSTRIDE + pre + rank] = idx;
    int t16 = 0;
#pragma unroll
    for (int w2 = 0; w2 < 16; w2++) t16 += wcount[w2];
    __syncthreads();
    total += t16;
  }
  int tiles = (total + 127) >> 7;
  if (tid == 0) {
    int lc = 0;
#pragma unroll
    for (int w2 = 0; w2 < 16; w2++) lc += lcw[w2];
    loadc_g[e] = lc;
    sbase = atomicAdd(ntiles, tiles);
    stot = total;
  }
  __syncthreads();
  if (tid < tiles) tiletab[sbase + tid] = e | (tid << 8);
  if (tid < 128) {
    int p = stot + tid;
    if (p < tiles * 128) lists[e * LSTRIDE + p] = DUMMY;
  }
}

// ---------------- losses ----------------
__global__ __launch_bounds__(1024) void k_losses(
    const float* __restrict__ blk, const int* __restrict__ loadc_g,
    float* __restrict__ out) {
  __shared__ float fin[9];
  int tid = threadIdx.x, lane = tid & 63, wv = tid >> 6;
  if (wv < 9) {
    float s = 0.f;
    for (int b = lane; b < 1024; b += 64) s += blk[b * 9 + wv];
#pragma unroll
    for (int off = 32; off >= 1; off >>= 1) s += __shfl_xor(s, off);
    if (lane == 0) fin[wv] = s;
  }
  __syncthreads();
  if (tid == 0) {
    float a = 0.f;
#pragma unroll
    for (int e = 0; e < 8; e++)
      a += (fin[e] * (1.f / 4096.f)) * ((float)loadc_g[e] * (1.f / 4096.f));
    out[NTOK * D_MODEL] = 8.f * a * 0.01f;
    out[NTOK * D_MODEL + 1] = fin[8] * (1.f / (4096.f * 8.f)) * 1e-4f;
  }
}

// -------- gemm1: h = silu(x@w1)*(x@w3); 128x128, BK=32, depth-3 vmcnt pipe ---
__global__ __launch_bounds__(256) void k_gemm1(
    const _Float16* __restrict__ xb, const _Float16* __restrict__ w1t,
    const _Float16* __restrict__ w3t, _Float16* __restrict__ h,
    const int* __restrict__ lists, const int* __restrict__ tiletab,
    const int* __restrict__ ntiles) {
  int ti = blockIdx.y;
  if (ti >= ntiles[0]) return;
  int ent = tiletab[ti];
  int e = ent & 15, mt = ent >> 8, nt = blockIdx.x;
  __shared__ __align__(16) _Float16 As[3][128 * 32];
  __shared__ __align__(16) _Float16 B1s[3][128 * 32];
  __shared__ __align__(16) _Float16 B3s[3][128 * 32];
  __shared__ int toks[128];
  int tid = threadIdx.x, lane = tid & 63, w = tid >> 6;
  if (tid < 128) toks[tid] = lists[e * LSTRIDE + mt * 128 + tid];
  __syncthreads();  // also drains vmcnt to 0 (baseline for counted waits)
  const _Float16* w1e = w1t + (size_t)e * D_FF * D_MODEL;
  const _Float16* w3e = w3t + (size_t)e * D_FF * D_MODEL;
  int n0 = nt * 128;
  const _Float16 *aS[2], *b1S[2], *b3S[2];
  int ldso[2];
#pragma unroll
  for (int c = 0; c < 2; c++) {
    int rt = w * 32 + c * 16 + (lane >> 2);
    int cg = (lane & 3) ^ ((rt >> 1) & 3);
    aS[c] = xb + (size_t)(toks[rt] >> 1) * D_MODEL + cg * 8;
    b1S[c] = w1e + (size_t)(n0 + rt) * D_MODEL + cg * 8;
    b3S[c] = w3e + (size_t)(n0 + rt) * D_MODEL + cg * 8;
    ldso[c] = (w * 32 + c * 16) * 32;
  }
  f32x4 acc1[4][4] = {};
  f32x4 acc3[4][4] = {};
  int wr = (w >> 1) * 64, wc = (w & 1) * 64;
  int aoff[4], boff[4];
#pragma unroll
  for (int i = 0; i < 4; i++) {
    int r = wr + i * 16 + (lane & 15);
    aoff[i] = r * 32 + (((lane >> 4) ^ ((r >> 1) & 3)) << 3);
    int rb = wc + i * 16 + (lane & 15);
    boff[i] = rb * 32 + (((lane >> 4) ^ ((rb >> 1) & 3)) << 3);
  }
#define G1_STAGE(T, BUF) do { \
  _Pragma("unroll") \
  for (int c = 0; c < 2; c++) { \
    gload16(aS[c] + (T) * 32, &As[BUF][ldso[c]]); \
    gload16(b1S[c] + (T) * 32, &B1s[BUF][ldso[c]]); \
    gload16(b3S[c] + (T) * 32, &B3s[BUF][ldso[c]]); \
  } } while (0)
  // prologue: 2 tiles in flight (12 outstanding loads)
  G1_STAGE(0, 0);
  G1_STAGE(1, 1);
#pragma unroll
  for (int t = 0; t < 16; t++) {
    if (t < 15) PIPE_BARRIER(6);   // drain tile t's 6 loads; t+1 stays in flight
    else        PIPE_BARRIER(0);
    if (t < 14) {
      const int nb = (t + 2) % 3;
      G1_STAGE(t + 2, nb);
    }
    const int buf = t % 3;
    half8 af[4], b1f[4], b3f[4];
#pragma unroll
    for (int i = 0; i < 4; i++) {
      af[i] = *(const half8*)(&As[buf][aoff[i]]);
      b1f[i] = *(const half8*)(&B1s[buf][boff[i]]);
      b3f[i] = *(const half8*)(&B3s[buf][boff[i]]);
    }
#pragma unroll
    for (int i = 0; i < 4; i++) {
#pragma unroll
      for (int j = 0; j < 4; j++) {
        acc1[i][j] = __builtin_amdgcn_mfma_f32_16x16x32_f16(af[i], b1f[j], acc1[i][j], 0, 0, 0);
        acc3[i][j] = __builtin_amdgcn_mfma_f32_16x16x32_f16(af[i], b3f[j], acc3[i][j], 0, 0, 0);
      }
    }
  }
#undef G1_STAGE
#pragma unroll
  for (int i = 0; i < 4; i++) {
    int rbase = wr + i * 16 + ((lane >> 4) << 2);
#pragma unroll
    for (int r = 0; r < 4; r++) {
      int m = rbase + r;
      int pair = toks[m];
      _Float16* hrow = h + (size_t)pair * D_FF + n0 + wc;
#pragma unroll
      for (int j = 0; j < 4; j++) {
        float g = acc1[i][j][r], u = acc3[i][j][r];
        float val = (g / (1.f + __expf(-g))) * u;
        hrow[j * 16 + (lane & 15)] = (_Float16)val;
      }
    }
  }
}

// -------- gemm2: pairout = wc*(h@w2); 128x64, BK=32, depth-3 vmcnt pipe ------
__global__ __launch_bounds__(256) void k_gemm2(
    const _Float16* __restrict__ h, const _Float16* __restrict__ w2t,
    float* __restrict__ pairout, const int* __restrict__ lists,
    const int* __restrict__ tiletab, const int* __restrict__ ntiles,
    const float* __restrict__ wcomb) {
  int ti = blockIdx.y;
  if (ti >= ntiles[0]) return;
  int ent = tiletab[ti];
  int e = ent & 15, mt = ent >> 8, nt = blockIdx.x;
  __shared__ __align__(16) _Float16 As[3][128 * 32];
  __shared__ __align__(16) _Float16 Bs[3][64 * 32];
  __shared__ int toks[128];
  __shared__ float wcs[128];
  int tid = threadIdx.x, lane = tid & 63, w = tid >> 6;
  if (tid < 128) {
    int p = lists[e * LSTRIDE + mt * 128 + tid];
    toks[tid] = p;
    wcs[tid] = (p < NPAIR) ? wcomb[p] : 0.f;
  }
  __syncthreads();  // drains vmcnt to 0
  const _Float16* w2e = w2t + (size_t)e * D_MODEL * D_FF;
  int n0 = nt * 64;
  const _Float16 *aS[2], *bS;
  int ldsa[2], ldsb;
#pragma unroll
  for (int c = 0; c < 2; c++) {
    int rt = w * 32 + c * 16 + (lane >> 2);
    int cg = (lane & 3) ^ ((rt >> 1) & 3);
    aS[c] = h + (size_t)toks[rt] * D_FF + cg * 8;
    ldsa[c] = (w * 32 + c * 16) * 32;
  }
  {
    int rt = w * 16 + (lane >> 2);
    int cg = (lane & 3) ^ ((rt >> 1) & 3);
    bS = w2e + (size_t)(n0 + rt) * D_FF + cg * 8;
    ldsb = (w * 16) * 32;
  }
  f32x4 acc[4][2] = {};
  int wr = (w >> 1) * 64, wc = (w & 1) * 32;
  int aoff[4], boff[2];
#pragma unroll
  for (int i = 0; i < 4; i++) {
    int r = wr + i * 16 + (lane & 15);
    aoff[i] = r * 32 + (((lane >> 4) ^ ((r >> 1) & 3)) << 3);
  }
#pragma unroll
  for (int j = 0; j < 2; j++) {
    int r = wc + j * 16 + (lane & 15);
    boff[j] = r * 32 + (((lane >> 4) ^ ((r >> 1) & 3)) << 3);
  }
#define G2_STAGE(T, BUF) do { \
  _Pragma("unroll") \
  for (int c = 0; c < 2; c++) gload16(aS[c] + (T) * 32, &As[BUF][ldsa[c]]); \
  gload16(bS + (T) * 32, &Bs[BUF][ldsb]); \
} while (0)
  G2_STAGE(0, 0);
  G2_STAGE(1, 1);
#pragma unroll
  for (int t = 0; t < 64; t++) {
    if (t < 63) PIPE_BARRIER(3);
    else        PIPE_BARRIER(0);
    if (t < 62) {
      const int nb = (t + 2) % 3;
      G2_STAGE(t + 2, nb);
    }
    const int buf = t % 3;
    half8 af[4], bf[2];
#pragma unroll
    for (int i = 0; i < 4; i++) af[i] = *(const half8*)(&As[buf][aoff[i]]);
#pragma unroll
    for (int j = 0; j < 2; j++) bf[j] = *(const half8*)(&Bs[buf][boff[j]]);
#pragma unroll
    for (int i = 0; i < 4; i++)
#pragma unroll
      for (int j = 0; j < 2; j++)
        acc[i][j] = __builtin_amdgcn_mfma_f32_16x16x32_f16(af[i], bf[j], acc[i][j], 0, 0, 0);
  }
#undef G2_STAGE
#pragma unroll
  for (int i = 0; i < 4; i++) {
    int rbase = wr + i * 16 + ((lane >> 4) << 2);
#pragma unroll
    for (int r = 0; r < 4; r++) {
      int m = rbase + r;
      int pair = toks[m];
      float wv_ = wcs[m];
      float* orow = pairout + (size_t)pair * D_MODEL + n0 + wc;
#pragma unroll
      for (int j = 0; j < 2; j++)
        orow[j * 16 + (lane & 15)] = acc[i][j][r] * wv_;
    }
  }
}

// ---------------- combine: out[n] = po[2n] + po[2n+1] (weights pre-applied) --
__global__ void k_combine(const float* __restrict__ po, float* __restrict__ out) {
  int gid = blockIdx.x * blockDim.x + threadIdx.x;
  int r = gid >> 7;
  int c = (gid & 127) * 4;
  const float4 a = *(const float4*)(po + (size_t)(2 * r) * D_MODEL + c);
  const float4 b = *(const float4*)(po + (size_t)(2 * r + 1) * D_MODEL + c);
  float4 o{a.x + b.x, a.y + b.y, a.z + b.z, a.w + b.w};
  *(float4*)(out + (size_t)r * D_MODEL + c) = o;
}

extern "C" void kernel_launch(void* const* d_in, const int* in_sizes, int n_in,
                              void* d_out, int out_size, void* d_ws, size_t ws_size,
                              hipStream_t stream) {
  const float* x = (const float*)d_in[0];
  const float* rw = (const float*)d_in[1];
  const float* w1 = (const float*)d_in[2];
  const float* w2 = (const float*)d_in[3];
  const float* w3 = (const float*)d_in[4];
  float* out = (float*)d_out;

  char* ws = (char*)d_ws;
  size_t o = 0;
  _Float16* w1t = (_Float16*)(ws + o); o += (size_t)NEXP * D_FF * D_MODEL * 2;
  _Float16* w3t = (_Float16*)(ws + o); o += (size_t)NEXP * D_FF * D_MODEL * 2;
  _Float16* w2t = (_Float16*)(ws + o); o += (size_t)NEXP * D_MODEL * D_FF * 2;
  _Float16* xb = (_Float16*)(ws + o); o += (size_t)(NTOK + 1) * D_MODEL * 2;
  _Float16* hbuf = (_Float16*)(ws + o); o += (size_t)(NPAIR + 1) * D_FF * 2;
  int* lists = (int*)(ws + o); o += (size_t)NEXP * LSTRIDE * 4;
  float* wcomb = (float*)(ws + o); o += (size_t)NPAIR * 4;
  int* topE = (int*)(ws + o); o += (size_t)NTOK * 4;
  float* blk = (float*)(ws + o); o += (size_t)1024 * 9 * 4;
  int* tiletab = (int*)(ws + o); o += MAXTILES * 4;
  int* ntiles = (int*)(ws + o); o += 16;
  int* loadc_g = (int*)(ws + o); o += 64;
  // pairout aliases the w1t/w3t region (dead after gemm1; gemm2 runs later)
  float* pairout = (float*)ws;  // (NPAIR+1)*D_MODEL*4 = 16.8MB < 33.5MB
  if (ws_size < o) return;  // workspace too small — refuse to corrupt

  k_prep<<<7168, 256, 0, stream>>>(x, rw, w1, w3, w2, w1t, w3t, w2t, xb, topE,
                                   wcomb, blk, ntiles);
  k_scatter<<<NEXP, 1024, 0, stream>>>(topE, lists, tiletab, ntiles, loadc_g);
  k_losses<<<1, 1024, 0, stream>>>(blk, loadc_g, out);
  k_gemm1<<<dim3(D_FF / 128, MAXTILES), 256, 0, stream>>>(xb, w1t, w3t, hbuf, lists, tiletab, ntiles);
  k_gemm2<<<dim3(D_MODEL / 64, MAXTILES), 256, 0, stream>>>(hbuf, w2t, pairout, lists, tiletab, ntiles, wcomb);
  k_combine<<<(NTOK * D_MODEL / 4 + 255) / 256, 256, 0, stream>>>(pairout, out);
}

// Round 6
// 284.007 us; speedup vs baseline: 1.4545x; 1.0354x over previous
//
#include <hip/hip_runtime.h>
#include <hip/hip_fp16.h>

#define D_MODEL 512
#define D_FF    2048
#define NEXP    8
#define NTOK    4096
#define NPAIR   8192
#define DUMMY   NPAIR
#define LSTRIDE 4224   // 4096 + 128 pad
#define MAXTILES 72
#define WBSTR   (4096 * 512)   // wB rows per expert * D_MODEL

typedef _Float16 half8  __attribute__((ext_vector_type(8)));
typedef _Float16 half2v __attribute__((ext_vector_type(2)));
typedef float    f32x4  __attribute__((ext_vector_type(4)));

__device__ __forceinline__ void gload16(const void* g, void* l) {
  __builtin_amdgcn_global_load_lds(
      (const __attribute__((address_space(1))) unsigned*)g,
      (__attribute__((address_space(3))) unsigned*)l, 16, 0, 0);
}

#define PIPE_BARRIER(N) do { \
  asm volatile("s_waitcnt vmcnt(" #N ")" ::: "memory"); \
  __builtin_amdgcn_s_barrier(); \
  asm volatile("" ::: "memory"); \
} while (0)

// ---- k_prep: [0,4096) w1/w3 -> wB interleaved; [4096,6144) w2t; rest router -
__global__ __launch_bounds__(256) void k_prep(
    const float* __restrict__ x, const float* __restrict__ rw,
    const float* __restrict__ w1, const float* __restrict__ w3,
    const float* __restrict__ w2, _Float16* __restrict__ wB,
    _Float16* __restrict__ w2t, _Float16* __restrict__ xb,
    int* __restrict__ topE, float* __restrict__ wcomb,
    float* __restrict__ blk, int* __restrict__ ntiles) {
  __shared__ float t[64][65];
  int tid = threadIdx.x;
  if (blockIdx.x < 6144) {
    int bt = blockIdx.x;
    const float* src; int rb, cb, e; bool isw3 = false, isw2 = (bt >= 4096);
    if (!isw2) {
      isw3 = (bt >= 2048);
      src = isw3 ? w3 : w1;
      int tt = bt & 2047; e = tt >> 8; int rem = tt & 255;
      rb = (rem >> 5) * 64; cb = (rem & 31) * 64;          // R=512(d), C=2048(f)
      src += (size_t)e * D_MODEL * D_FF;
    } else {
      int tt = bt - 4096; e = tt >> 8; int rem = tt & 255;
      src = w2;
      rb = (rem >> 3) * 64; cb = (rem & 7) * 64;           // R=2048(f), C=512(d)
      src += (size_t)e * D_FF * D_MODEL;
    }
    int C = isw2 ? D_MODEL : D_FF;
    int tx = tid & 15, ty = tid >> 4;
#pragma unroll
    for (int i = 0; i < 4; i++) {
      float4 v = *(const float4*)(src + (size_t)(rb + ty + i * 16) * C + cb + tx * 4);
      t[ty + i * 16][tx * 4 + 0] = v.x;
      t[ty + i * 16][tx * 4 + 1] = v.y;
      t[ty + i * 16][tx * 4 + 2] = v.z;
      t[ty + i * 16][tx * 4 + 3] = v.w;
    }
    __syncthreads();
    int tx2 = tid & 31, ty2 = tid >> 5;
#pragma unroll
    for (int i = 0; i < 8; i++) {
      int c = ty2 + i * 8;      // local col of src (the new row index)
      int r = tx2 * 2;          // local row of src (contiguous in dst)
      half2v p = {(_Float16)t[r][c], (_Float16)t[r + 1][c]};
      if (!isw2) {
        int f = cb + c;
        int j = ((f >> 5) << 6) + (isw3 ? 32 : 0) + (f & 31);
        *(half2v*)(wB + (size_t)e * WBSTR + (size_t)j * D_MODEL + rb + r) = p;
      } else {
        *(half2v*)(w2t + (size_t)e * D_MODEL * D_FF + (size_t)(cb + c) * D_FF + rb + r) = p;
      }
    }
  } else {
    int bx = blockIdx.x - 6144;
    __shared__ float s_imp[NEXP];
    __shared__ float s_z;
    if (tid < NEXP) s_imp[tid] = 0.f;
    if (tid == 0) s_z = 0.f;
    if (bx == 0 && tid == 0) ntiles[0] = 0;
    __syncthreads();
    int wave = tid >> 6, lane = tid & 63;
    int n = bx * 4 + wave;
    const float* xr = x + (size_t)n * D_MODEL;
    float acc[8] = {0, 0, 0, 0, 0, 0, 0, 0};
    float4 v0 = *(const float4*)(xr + lane * 8);
    float4 v1 = *(const float4*)(xr + lane * 8 + 4);
    float xs[8] = {v0.x, v0.y, v0.z, v0.w, v1.x, v1.y, v1.z, v1.w};
    half8 hx = {(_Float16)xs[0], (_Float16)xs[1], (_Float16)xs[2], (_Float16)xs[3],
                (_Float16)xs[4], (_Float16)xs[5], (_Float16)xs[6], (_Float16)xs[7]};
    *(half8*)(xb + (size_t)n * D_MODEL + lane * 8) = hx;
#pragma unroll
    for (int j = 0; j < 8; j++) {
      const float4* w4 = (const float4*)(rw + (size_t)(lane * 8 + j) * NEXP);
      float4 wa = w4[0], wb = w4[1];
      acc[0] += xs[j] * wa.x; acc[1] += xs[j] * wa.y;
      acc[2] += xs[j] * wa.z; acc[3] += xs[j] * wa.w;
      acc[4] += xs[j] * wb.x; acc[5] += xs[j] * wb.y;
      acc[6] += xs[j] * wb.z; acc[7] += xs[j] * wb.w;
    }
#pragma unroll
    for (int off = 32; off >= 1; off >>= 1) {
#pragma unroll
      for (int e = 0; e < 8; e++) acc[e] += __shfl_xor(acc[e], off);
    }
    if (lane == 0) {
      float z = 0.f;
#pragma unroll
      for (int e = 0; e < 8; e++) z += acc[e] * acc[e];
      float m = acc[0];
#pragma unroll
      for (int e = 1; e < 8; e++) m = fmaxf(m, acc[e]);
      float p[8], s = 0.f;
#pragma unroll
      for (int e = 0; e < 8; e++) { p[e] = expf(acc[e] - m); s += p[e]; }
      float inv = 1.f / s;
#pragma unroll
      for (int e = 0; e < 8; e++) p[e] *= inv;
      int e0 = 0; float p0 = p[0];
#pragma unroll
      for (int e = 1; e < 8; e++) if (p[e] > p0) { p0 = p[e]; e0 = e; }
      int e1 = -1; float p1 = -1.f;
#pragma unroll
      for (int e = 0; e < 8; e++) if (e != e0 && p[e] > p1) { p1 = p[e]; e1 = e; }
      float wsum = p0 + p1;
      topE[n] = e0 | (e1 << 4);
      wcomb[2 * n] = p0 / wsum;
      wcomb[2 * n + 1] = p1 / wsum;
#pragma unroll
      for (int e = 0; e < 8; e++) atomicAdd(&s_imp[e], p[e]);
      atomicAdd(&s_z, z);
    }
    __syncthreads();
    if (tid < 8) blk[bx * 9 + tid] = s_imp[tid];
    if (tid == 8) blk[bx * 9 + 8] = s_z;
  }
}

// ------- scatter: 8 blocks (1/expert): build list, pad, tile table, load -----
__global__ __launch_bounds__(1024) void k_scatter(
    const int* __restrict__ topE, int* __restrict__ lists,
    int* __restrict__ tiletab, int* __restrict__ ntiles,
    int* __restrict__ loadc_g) {
  int e = blockIdx.x;
  __shared__ int wcount[16];
  __shared__ int lcw[16];
  __shared__ int sbase;
  __shared__ int stot;
  int tid = threadIdx.x, lane = tid & 63, wv = tid >> 6;
  if (lane == 0) lcw[wv] = 0;
  int total = 0;
  for (int c = 0; c < 8; c++) {
    int idx = c * 1024 + tid;
    int te = topE[idx >> 1];
    int ee = (idx & 1) ? ((te >> 4) & 15) : (te & 15);
    bool mine = (ee == e);
    unsigned long long bal = __ballot(mine);
    unsigned long long balL = __ballot(mine && !(idx & 1));  // convergent
    int rank = __popcll(bal & ((1ull << lane) - 1ull));
    if (lane == 0) {
      wcount[wv] = __popcll(bal);
      lcw[wv] += __popcll(balL);
    }
    __syncthreads();
    int pre = total;
    for (int w2 = 0; w2 < wv; w2++) pre += wcount[w2];
    if (mine) lists[e * LSTRIDE + pre + rank] = idx;
    int t16 = 0;
#pragma unroll
    for (int w2 = 0; w2 < 16; w2++) t16 += wcount[w2];
    __syncthreads();
    total += t16;
  }
  int tiles = (total + 127) >> 7;
  if (tid == 0) {
    int lc = 0;
#pragma unroll
    for (int w2 = 0; w2 < 16; w2++) lc += lcw[w2];
    loadc_g[e] = lc;
    sbase = atomicAdd(ntiles, tiles);
    stot = total;
  }
  __syncthreads();
  if (tid < tiles) tiletab[sbase + tid] = e | (tid << 8);
  if (tid < 128) {
    int p = stot + tid;
    if (p < tiles * 128) lists[e * LSTRIDE + p] = DUMMY;
  }
}

// ---------------- losses ----------------
__global__ __launch_bounds__(1024) void k_losses(
    const float* __restrict__ blk, const int* __restrict__ loadc_g,
    float* __restrict__ out) {
  __shared__ float fin[9];
  int tid = threadIdx.x, lane = tid & 63, wv = tid >> 6;
  if (wv < 9) {
    float s = 0.f;
    for (int b = lane; b < 1024; b += 64) s += blk[b * 9 + wv];
#pragma unroll
    for (int off = 32; off >= 1; off >>= 1) s += __shfl_xor(s, off);
    if (lane == 0) fin[wv] = s;
  }
  __syncthreads();
  if (tid == 0) {
    float a = 0.f;
#pragma unroll
    for (int e = 0; e < 8; e++)
      a += (fin[e] * (1.f / 4096.f)) * ((float)loadc_g[e] * (1.f / 4096.f));
    out[NTOK * D_MODEL] = 8.f * a * 0.01f;
    out[NTOK * D_MODEL + 1] = fin[8] * (1.f / (4096.f * 8.f)) * 1e-4f;
  }
}

// -------- gemm1: 128x256 tile (256 wB-cols = 128 h-cols g|u), BK=64, 8 waves -
__global__ __launch_bounds__(512) void k_gemm1(
    const _Float16* __restrict__ xb, const _Float16* __restrict__ wB,
    _Float16* __restrict__ h, const int* __restrict__ lists,
    const int* __restrict__ tiletab, const int* __restrict__ ntiles) {
  int ti = blockIdx.y;
  if (ti >= ntiles[0]) return;
  int ent = tiletab[ti];
  int e = ent & 15, mt = ent >> 8, nt = blockIdx.x;
  __shared__ __align__(16) _Float16 Asl[2][128 * 64];
  __shared__ __align__(16) _Float16 Bsl[2][256 * 64];
  __shared__ int toks[128];
  int tid = threadIdx.x, lane = tid & 63, w = tid >> 6;
  if (tid < 128) toks[tid] = lists[e * LSTRIDE + mt * 128 + tid];
  __syncthreads();
  const _Float16* wBe = wB + (size_t)e * WBSTR;
  int l3 = lane >> 3, l7 = lane & 7;
  const _Float16* aSrc[2];
  const _Float16* bSrc[4];
#pragma unroll
  for (int g = 0; g < 2; g++) {
    int r = w * 16 + g * 8 + l3;
    aSrc[g] = xb + (size_t)(toks[r] >> 1) * D_MODEL + ((l7 ^ (r & 7)) << 3);
  }
#pragma unroll
  for (int g = 0; g < 4; g++) {
    int r = w * 32 + g * 8 + l3;
    bSrc[g] = wBe + (size_t)(nt * 256 + r) * D_MODEL + ((l7 ^ (r & 7)) << 3);
  }
  int wm = w >> 2, wn = w & 3;
  int la = lane & 15, lh = lane >> 4;
  int aoff[4][2], boff[4][2];
#pragma unroll
  for (int mf = 0; mf < 4; mf++)
#pragma unroll
    for (int kh = 0; kh < 2; kh++) {
      int r = wm * 64 + mf * 16 + la;
      aoff[mf][kh] = r * 64 + (((kh * 4 + lh) ^ (r & 7)) << 3);
      int rb = wn * 64 + mf * 16 + la;
      boff[mf][kh] = rb * 64 + (((kh * 4 + lh) ^ (rb & 7)) << 3);
    }
  f32x4 acc[4][4] = {};
  // prologue: stage tile 0 -> buf0
#pragma unroll
  for (int g = 0; g < 2; g++) gload16(aSrc[g], &Asl[0][(w * 16 + g * 8) * 64]);
#pragma unroll
  for (int g = 0; g < 4; g++) gload16(bSrc[g], &Bsl[0][(w * 32 + g * 8) * 64]);
  PIPE_BARRIER(0);
#pragma unroll
  for (int t = 0; t < 8; t++) {
    const int cur = t & 1, nb = cur ^ 1;
    const int k1 = (t + 1) * 64;
    if (t < 7) {
#pragma unroll
      for (int g = 0; g < 2; g++) gload16(aSrc[g] + k1, &Asl[nb][(w * 16 + g * 8) * 64]);
    }
    half8 af[4], bf[4];
#pragma unroll
    for (int nf = 0; nf < 4; nf++) bf[nf] = *(const half8*)(&Bsl[cur][boff[nf][0]]);
#pragma unroll
    for (int mf = 0; mf < 4; mf++) af[mf] = *(const half8*)(&Asl[cur][aoff[mf][0]]);
#pragma unroll
    for (int mf = 0; mf < 4; mf++)
#pragma unroll
      for (int nf = 0; nf < 4; nf++)
        acc[mf][nf] = __builtin_amdgcn_mfma_f32_16x16x32_f16(af[mf], bf[nf], acc[mf][nf], 0, 0, 0);
    if (t < 7) {
#pragma unroll
      for (int g = 0; g < 4; g++) gload16(bSrc[g] + k1, &Bsl[nb][(w * 32 + g * 8) * 64]);
    }
#pragma unroll
    for (int nf = 0; nf < 4; nf++) bf[nf] = *(const half8*)(&Bsl[cur][boff[nf][1]]);
#pragma unroll
    for (int mf = 0; mf < 4; mf++) af[mf] = *(const half8*)(&Asl[cur][aoff[mf][1]]);
#pragma unroll
    for (int mf = 0; mf < 4; mf++)
#pragma unroll
      for (int nf = 0; nf < 4; nf++)
        acc[mf][nf] = __builtin_amdgcn_mfma_f32_16x16x32_f16(af[mf], bf[nf], acc[mf][nf], 0, 0, 0);
    PIPE_BARRIER(0);
  }
  // epilogue: silu(g)*u ; acc[.][nf] pairs with acc[.][nf+2] (same h-col)
  int fbase = (nt * 4 + wn) * 32;
#pragma unroll
  for (int mf = 0; mf < 4; mf++) {
    int mb = wm * 64 + mf * 16 + (lh << 2);
#pragma unroll
    for (int q = 0; q < 4; q++) {
      int m = mb + q;
      int pair = toks[m];
      _Float16* hrow = h + (size_t)pair * D_FF + fbase;
#pragma unroll
      for (int nf = 0; nf < 2; nf++) {
        float g = acc[mf][nf][q], u = acc[mf][nf + 2][q];
        hrow[nf * 16 + la] = (_Float16)((g / (1.f + __expf(-g))) * u);
      }
    }
  }
}

// -------- gemm2: 128x256 tile, BK=64, split-K=2, f32 partials ----------------
__global__ __launch_bounds__(512) void k_gemm2(
    const _Float16* __restrict__ h, const _Float16* __restrict__ w2t,
    float* __restrict__ po2, const int* __restrict__ lists,
    const int* __restrict__ tiletab, const int* __restrict__ ntiles,
    const float* __restrict__ wcomb) {
  int ti = blockIdx.y;
  if (ti >= ntiles[0]) return;
  int ent = tiletab[ti];
  int e = ent & 15, mt = ent >> 8;
  int nt = blockIdx.x & 1, ks = blockIdx.x >> 1;
  __shared__ __align__(16) _Float16 Asl[2][128 * 64];
  __shared__ __align__(16) _Float16 Bsl[2][256 * 64];
  __shared__ int toks[128];
  __shared__ float wcs[128];
  int tid = threadIdx.x, lane = tid & 63, w = tid >> 6;
  if (tid < 128) {
    int p = lists[e * LSTRIDE + mt * 128 + tid];
    toks[tid] = p;
    wcs[tid] = (p < NPAIR) ? wcomb[p] : 0.f;
  }
  __syncthreads();
  const _Float16* w2e = w2t + (size_t)e * D_MODEL * D_FF;
  const int kb = ks * 1024;
  int l3 = lane >> 3, l7 = lane & 7;
  const _Float16* aSrc[2];
  const _Float16* bSrc[4];
#pragma unroll
  for (int g = 0; g < 2; g++) {
    int r = w * 16 + g * 8 + l3;
    aSrc[g] = h + (size_t)toks[r] * D_FF + kb + ((l7 ^ (r & 7)) << 3);
  }
#pragma unroll
  for (int g = 0; g < 4; g++) {
    int r = w * 32 + g * 8 + l3;
    bSrc[g] = w2e + (size_t)(nt * 256 + r) * D_FF + kb + ((l7 ^ (r & 7)) << 3);
  }
  int wm = w >> 2, wn = w & 3;
  int la = lane & 15, lh = lane >> 4;
  int aoff[4][2], boff[4][2];
#pragma unroll
  for (int mf = 0; mf < 4; mf++)
#pragma unroll
    for (int kh = 0; kh < 2; kh++) {
      int r = wm * 64 + mf * 16 + la;
      aoff[mf][kh] = r * 64 + (((kh * 4 + lh) ^ (r & 7)) << 3);
      int rb = wn * 64 + mf * 16 + la;
      boff[mf][kh] = rb * 64 + (((kh * 4 + lh) ^ (rb & 7)) << 3);
    }
  f32x4 acc[4][4] = {};
#pragma unroll
  for (int g = 0; g < 2; g++) gload16(aSrc[g], &Asl[0][(w * 16 + g * 8) * 64]);
#pragma unroll
  for (int g = 0; g < 4; g++) gload16(bSrc[g], &Bsl[0][(w * 32 + g * 8) * 64]);
  PIPE_BARRIER(0);
#pragma unroll 2
  for (int t = 0; t < 16; t++) {
    const int cur = t & 1, nb = cur ^ 1;
    const int k1 = (t + 1) * 64;
    if (t < 15) {
#pragma unroll
      for (int g = 0; g < 2; g++) gload16(aSrc[g] + k1, &Asl[nb][(w * 16 + g * 8) * 64]);
    }
    half8 af[4], bf[4];
#pragma unroll
    for (int nf = 0; nf < 4; nf++) bf[nf] = *(const half8*)(&Bsl[cur][boff[nf][0]]);
#pragma unroll
    for (int mf = 0; mf < 4; mf++) af[mf] = *(const half8*)(&Asl[cur][aoff[mf][0]]);
#pragma unroll
    for (int mf = 0; mf < 4; mf++)
#pragma unroll
      for (int nf = 0; nf < 4; nf++)
        acc[mf][nf] = __builtin_amdgcn_mfma_f32_16x16x32_f16(af[mf], bf[nf], acc[mf][nf], 0, 0, 0);
    if (t < 15) {
#pragma unroll
      for (int g = 0; g < 4; g++) gload16(bSrc[g] + k1, &Bsl[nb][(w * 32 + g * 8) * 64]);
    }
#pragma unroll
    for (int nf = 0; nf < 4; nf++) bf[nf] = *(const half8*)(&Bsl[cur][boff[nf][1]]);
#pragma unroll
    for (int mf = 0; mf < 4; mf++) af[mf] = *(const half8*)(&Asl[cur][aoff[mf][1]]);
#pragma unroll
    for (int mf = 0; mf < 4; mf++)
#pragma unroll
      for (int nf = 0; nf < 4; nf++)
        acc[mf][nf] = __builtin_amdgcn_mfma_f32_16x16x32_f16(af[mf], bf[nf], acc[mf][nf], 0, 0, 0);
    PIPE_BARRIER(0);
  }
  int dbase = nt * 256 + wn * 64;
#pragma unroll
  for (int mf = 0; mf < 4; mf++) {
    int mb = wm * 64 + mf * 16 + (lh << 2);
#pragma unroll
    for (int q = 0; q < 4; q++) {
      int m = mb + q;
      int pair = toks[m];
      if (pair < NPAIR) {
        float wv = wcs[m];
        float* orow = po2 + ((size_t)ks * NPAIR + pair) * D_MODEL + dbase;
#pragma unroll
        for (int nf = 0; nf < 4; nf++)
          orow[nf * 16 + la] = acc[mf][nf][q] * wv;
      }
    }
  }
}

// ------- combine: out[n] = sum over {split}x{2 pairs} (weights pre-applied) --
__global__ void k_combine(const float* __restrict__ po2, float* __restrict__ out) {
  int gid = blockIdx.x * blockDim.x + threadIdx.x;
  int r = gid >> 7;
  int c = (gid & 127) * 4;
  const float4 a0 = *(const float4*)(po2 + (size_t)(2 * r) * D_MODEL + c);
  const float4 a1 = *(const float4*)(po2 + (size_t)(2 * r + 1) * D_MODEL + c);
  const float4 b0 = *(const float4*)(po2 + (size_t)(NPAIR + 2 * r) * D_MODEL + c);
  const float4 b1 = *(const float4*)(po2 + (size_t)(NPAIR + 2 * r + 1) * D_MODEL + c);
  float4 o{a0.x + a1.x + b0.x + b1.x, a0.y + a1.y + b0.y + b1.y,
           a0.z + a1.z + b0.z + b1.z, a0.w + a1.w + b0.w + b1.w};
  *(float4*)(out + (size_t)r * D_MODEL + c) = o;
}

extern "C" void kernel_launch(void* const* d_in, const int* in_sizes, int n_in,
                              void* d_out, int out_size, void* d_ws, size_t ws_size,
                              hipStream_t stream) {
  const float* x = (const float*)d_in[0];
  const float* rw = (const float*)d_in[1];
  const float* w1 = (const float*)d_in[2];
  const float* w2 = (const float*)d_in[3];
  const float* w3 = (const float*)d_in[4];
  float* out = (float*)d_out;

  char* ws = (char*)d_ws;
  size_t o = 0;
  _Float16* wB = (_Float16*)(ws + o); o += (size_t)NEXP * WBSTR * 2;           // 33.55 MB
  _Float16* w2t = (_Float16*)(ws + o); o += (size_t)NEXP * D_MODEL * D_FF * 2; // 16.8 MB
  _Float16* xb = (_Float16*)(ws + o); o += (size_t)(NTOK + 1) * D_MODEL * 2;
  _Float16* hbuf = (_Float16*)(ws + o); o += (size_t)(NPAIR + 1) * D_FF * 2;
  int* lists = (int*)(ws + o); o += (size_t)NEXP * LSTRIDE * 4;
  float* wcomb = (float*)(ws + o); o += (size_t)NPAIR * 4;
  int* topE = (int*)(ws + o); o += (size_t)NTOK * 4;
  float* blk = (float*)(ws + o); o += (size_t)1024 * 9 * 4;
  int* tiletab = (int*)(ws + o); o += MAXTILES * 4;
  int* ntiles = (int*)(ws + o); o += 16;
  int* loadc_g = (int*)(ws + o); o += 64;
  // po2 (2 splits x 8192 x 512 f32 = 33,554,432 B) aliases wB exactly
  // (wB dead after gemm1; gemm2/combine run later)
  float* po2 = (float*)ws;
  if (ws_size < o) return;  // workspace too small — refuse to corrupt

  k_prep<<<7168, 256, 0, stream>>>(x, rw, w1, w3, w2, wB, w2t, xb, topE,
                                   wcomb, blk, ntiles);
  k_scatter<<<NEXP, 1024, 0, stream>>>(topE, lists, tiletab, ntiles, loadc_g);
  k_losses<<<1, 1024, 0, stream>>>(blk, loadc_g, out);
  k_gemm1<<<dim3(16, MAXTILES), 512, 0, stream>>>(xb, wB, hbuf, lists, tiletab, ntiles);
  k_gemm2<<<dim3(4, MAXTILES), 512, 0, stream>>>(hbuf, w2t, po2, lists, tiletab, ntiles, wcomb);
  k_combine<<<(NTOK * D_MODEL / 4 + 255) / 256, 256, 0, stream>>>(po2, out);
}